// Round 11
// baseline (321.440 us; speedup 1.0000x reference)
//
#include <hip/hip_runtime.h>
#include <stdint.h>

// PointNet EdgeConv, 2 layers. Round 11.
// R5:  packed v_pk_fma_f32.                                    337 us
// R8:  MLP2 via v_mfma_f32_32x32x16_bf16.                      331 us
// R10: atomic-free bucket sort (range_total folded into scan). 278 us
// R11: RANGE-RESIDENT AGGREGATION: one block per 128-dst range keeps
//      agg[128][32] ord-encoded in LDS; chunks of 256 edges -> hid -> MFMA ->
//      ds_max_u32 directly from C regs -> one coalesced relu'd write.
//      Deletes bucket_sort/init/finalize kernels, row_ptr/cnt, all global
//      atomics, and the m-matrix LDS round trip. 11 -> 8 launches.

#define BS 256
#define K1_EDGES 4096  // edges staged per block in scatter pass

typedef float v2f __attribute__((ext_vector_type(2)));
typedef __attribute__((ext_vector_type(8))) short bf16x8;
typedef __attribute__((ext_vector_type(16))) float f32x16;

__device__ __forceinline__ unsigned ordenc(float f) {
    unsigned u = __float_as_uint(f);
    return (u & 0x80000000u) ? ~u : (u | 0x80000000u);
}
__device__ __forceinline__ float orddec(unsigned o) {
    unsigned u = (o & 0x80000000u) ? (o ^ 0x80000000u) : ~o;
    return __uint_as_float(u);
}
#define ORD_NEG_INF 0x007FFFFFu  // ordenc(-inf)

__device__ __forceinline__ unsigned pack_bf16_rne(float x, float y) {
    unsigned ux = __float_as_uint(x), uy = __float_as_uint(y);
    ux = ux + 0x7FFFu + ((ux >> 16) & 1u);
    uy = uy + 0x7FFFu + ((uy >> 16) & 1u);
    return (ux >> 16) | (uy & 0xFFFF0000u);
}

// ---------------- pass 1a: per-block range histogram (LDS only) -------------
__global__ __launch_bounds__(BS) void bucket_hist_kernel(const int* __restrict__ ei, int E,
                                                         int NRP, int* __restrict__ blockHist) {
    __shared__ int hist[1024];
    const int tid = threadIdx.x;
    for (int r = tid; r < 1024; r += BS) hist[r] = 0;
    __syncthreads();
    const int base = blockIdx.x * K1_EDGES;
    const int M = min(K1_EDGES, E - base);
    for (int i = tid; i < M; i += BS) atomicAdd(&hist[ei[E + base + i] >> 7], 1);
    __syncthreads();
    for (int r = tid; r < NRP; r += BS) blockHist[blockIdx.x * NRP + r] = hist[r];
}

// ---------------- pass 2a: per-(block,range) LOCAL prefixes + range totals --
__global__ __launch_bounds__(512) void off_scan_kernel(const int* __restrict__ blockHist,
                                                       int NB1, int NRP,
                                                       int* __restrict__ off,
                                                       int* __restrict__ total) {
    const int r = (blockIdx.x * 512 + threadIdx.x) >> 6;
    const int lane = threadIdx.x & 63;
    if (r >= NRP) return;
    int carry = 0;
    const int chunks = (NB1 + 63) / 64;
    for (int c = 0; c < chunks; ++c) {
        const int b = c * 64 + lane;
        const int v = (b < NB1) ? blockHist[b * NRP + r] : 0;
        int x = v;
#pragma unroll
        for (int d = 1; d < 64; d <<= 1) {
            int y = __shfl_up(x, d, 64);
            if (lane >= d) x += y;
        }
        if (b < NB1) off[b * NRP + r] = carry + (x - v);
        carry += __shfl(x, 63, 64);
    }
    if (lane == 0) total[r] = carry;
}

// ---------------- pass 2b: exclusive scan of totals -> rangeBase ------------
__global__ __launch_bounds__(1024) void range_scan_kernel(const int* __restrict__ total,
                                                          int NRP, int* __restrict__ rangeBase) {
    __shared__ int s[1024];
    const int t = threadIdx.x;
    const int v = (t < NRP) ? total[t] : 0;
    s[t] = v;
    __syncthreads();
    for (int off = 1; off < 1024; off <<= 1) {
        int add = (t >= off) ? s[t - off] : 0;
        __syncthreads();
        s[t] += add;
        __syncthreads();
    }
    if (t < NRP) rangeBase[t] = s[t] - v;
}

// ---------------- pass 1b: LDS-ranked scatter into range buckets ------------
__global__ __launch_bounds__(BS) void bucket_scatter_kernel(
    const int* __restrict__ ei, int E, int NRP, const int* __restrict__ off,
    const int* __restrict__ rangeBase, int2* __restrict__ sedgeB) {
    __shared__ int2 stage[K1_EDGES];          // 32 KB
    __shared__ unsigned short inv[K1_EDGES];  // 8 KB
    __shared__ int hist[1024], start[1024], cursor[1024];
    __shared__ int ts[BS];
    const int tid = threadIdx.x;
    for (int r = tid; r < 1024; r += BS) hist[r] = 0;
    __syncthreads();
    const int base = blockIdx.x * K1_EDGES;
    const int M = min(K1_EDGES, E - base);
    for (int i = tid; i < M; i += BS) {
        const int2 p = make_int2(ei[base + i], ei[E + base + i]);
        stage[i] = p;
        atomicAdd(&hist[p.y >> 7], 1);
    }
    __syncthreads();
    {
        const int i0 = tid * 4;
        const int l0 = hist[i0], l1 = hist[i0 + 1], l2 = hist[i0 + 2], l3 = hist[i0 + 3];
        const int tsum = l0 + l1 + l2 + l3;
        ts[tid] = tsum;
        __syncthreads();
        for (int off2 = 1; off2 < BS; off2 <<= 1) {
            int add = (tid >= off2) ? ts[tid - off2] : 0;
            __syncthreads();
            ts[tid] += add;
            __syncthreads();
        }
        const int texcl = ts[tid] - tsum;
        start[i0] = texcl;
        start[i0 + 1] = texcl + l0;
        start[i0 + 2] = texcl + l0 + l1;
        start[i0 + 3] = texcl + l0 + l1 + l2;
        cursor[i0] = start[i0];
        cursor[i0 + 1] = start[i0 + 1];
        cursor[i0 + 2] = start[i0 + 2];
        cursor[i0 + 3] = start[i0 + 3];
    }
    __syncthreads();
    for (int i = tid; i < M; i += BS) {
        const int pos = atomicAdd(&cursor[stage[i].y >> 7], 1);
        inv[pos] = (unsigned short)i;
    }
    __syncthreads();
    const int* offb = off + blockIdx.x * NRP;
    for (int j = tid; j < M; j += BS) {
        const int2 p = stage[inv[j]];
        const int r = p.y >> 7;
        sedgeB[rangeBase[r] + offb[r] + (j - start[r])] = p;  // contiguous runs
    }
}

// ---------------- per-node U/V precompute ----------------
__global__ __launch_bounds__(BS) void prep1_kernel(const float* __restrict__ pos,
                                                   const float* __restrict__ Wa,
                                                   const float* __restrict__ ba,
                                                   float* __restrict__ U, float* __restrict__ V,
                                                   int N) {
    int n = blockIdx.x * BS + threadIdx.x;
    if (n >= N) return;
    const float p[3] = {pos[3 * n], pos[3 * n + 1], pos[3 * n + 2]};
    v2f u[16], v[16];
#pragma unroll
    for (int g = 0; g < 16; ++g) {
        u[g] = *reinterpret_cast<const v2f*>(&ba[g * 2]);
        v2f z = {0.0f, 0.0f};
        v[g] = z;
    }
#pragma unroll
    for (int i = 0; i < 3; ++i) {
        const v2f f = {p[i], p[i]};
#pragma unroll
        for (int g = 0; g < 16; ++g) {
            const v2f wA = *reinterpret_cast<const v2f*>(&Wa[i * 32 + g * 2]);
            const v2f wB = *reinterpret_cast<const v2f*>(&Wa[(i + 3) * 32 + g * 2]);
            u[g] = __builtin_elementwise_fma(f, wA + wB, u[g]);
            v[g] = __builtin_elementwise_fma(f, wB, v[g]);
        }
    }
    float4* Up = reinterpret_cast<float4*>(U + (size_t)n * 32);
    float4* Vp = reinterpret_cast<float4*>(V + (size_t)n * 32);
#pragma unroll
    for (int q = 0; q < 8; ++q) {
        Up[q] = make_float4(u[2 * q].x, u[2 * q].y, u[2 * q + 1].x, u[2 * q + 1].y);
        Vp[q] = make_float4(v[2 * q].x, v[2 * q].y, v[2 * q + 1].x, v[2 * q + 1].y);
    }
}

// Layer 2 prep: h1 is plain relu'd floats now.
__global__ __launch_bounds__(BS) void prep2_kernel(const float* __restrict__ pos,
                                                   const float* __restrict__ h1,
                                                   const float* __restrict__ Wa,
                                                   const float* __restrict__ ba,
                                                   float* __restrict__ U, float* __restrict__ V,
                                                   int N) {
    int n = blockIdx.x * BS + threadIdx.x;
    if (n >= N) return;
    float h[32];
    const float4* hp = reinterpret_cast<const float4*>(h1 + (size_t)n * 32);
#pragma unroll
    for (int q = 0; q < 8; ++q) {
        float4 t = hp[q];
        h[4 * q + 0] = t.x;
        h[4 * q + 1] = t.y;
        h[4 * q + 2] = t.z;
        h[4 * q + 3] = t.w;
    }
    const float p[3] = {pos[3 * n], pos[3 * n + 1], pos[3 * n + 2]};
    v2f u[16], v[16];
#pragma unroll
    for (int g = 0; g < 16; ++g) {
        u[g] = *reinterpret_cast<const v2f*>(&ba[g * 2]);
        v2f z = {0.0f, 0.0f};
        v[g] = z;
    }
#pragma unroll
    for (int i = 0; i < 32; ++i) {
        const v2f f = {h[i], h[i]};
#pragma unroll
        for (int g = 0; g < 16; ++g) {
            const v2f w = *reinterpret_cast<const v2f*>(&Wa[i * 32 + g * 2]);
            u[g] = __builtin_elementwise_fma(f, w, u[g]);
        }
    }
#pragma unroll
    for (int i = 0; i < 3; ++i) {
        const v2f f = {p[i], p[i]};
#pragma unroll
        for (int g = 0; g < 16; ++g) {
            const v2f w = *reinterpret_cast<const v2f*>(&Wa[(32 + i) * 32 + g * 2]);
            u[g] = __builtin_elementwise_fma(f, w, u[g]);
            v[g] = __builtin_elementwise_fma(f, w, v[g]);
        }
    }
    float4* Up = reinterpret_cast<float4*>(U + (size_t)n * 32);
    float4* Vp = reinterpret_cast<float4*>(V + (size_t)n * 32);
#pragma unroll
    for (int q = 0; q < 8; ++q) {
        Up[q] = make_float4(u[2 * q].x, u[2 * q].y, u[2 * q + 1].x, u[2 * q + 1].y);
        Vp[q] = make_float4(v[2 * q].x, v[2 * q].y, v[2 * q + 1].x, v[2 * q + 1].y);
    }
}

// ---------------- range-resident edge kernel ----------------
// One block per 128-dst range. LDS (39936 B, 4 blocks/CU):
//   hidb [256*20] dwords : hid bf16 pairs, stride 20 (A-fragment layout)
//   wbt  [512]    dwords : Wb^T bf16 pairs (B fragments)
//   sagg [128*32] dwords : ord-encoded running max
//   sdst [256]    ints   : dst&127 per staged edge
// Chunks of 256 edges: gather U/V -> hid -> MFMA -> ds_max_u32 from C regs.
// Tail clamps to last edge: duplicate max is idempotent. Final coalesced
// relu'd float write (also maps deg-0 -inf -> 0).
__global__ __launch_bounds__(BS, 4) void edge_range_kernel(
    const float4* __restrict__ U, const float4* __restrict__ V,
    const int2* __restrict__ sedgeB, const int* __restrict__ rangeBase,
    const int* __restrict__ total, const float* __restrict__ Wb,
    const float* __restrict__ bb, float* __restrict__ out, int N) {
    __shared__ __align__(16) unsigned hidb[256 * 20];
    __shared__ __align__(16) unsigned wbt[512];
    __shared__ unsigned sagg[128 * 32];
    __shared__ int sdst[256];

    const int r = blockIdx.x;
    const int tid = threadIdx.x;
    const int base = rangeBase[r];
    const int M = total[r];

    for (int i = tid; i < 4096; i += BS) sagg[i] = ORD_NEG_INF;
    {
        const int n = tid & 31;
        const int p = (tid >> 5) * 2;
        wbt[n * 16 + p + 0] = pack_bf16_rne(Wb[(2 * p + 0) * 32 + n], Wb[(2 * p + 1) * 32 + n]);
        wbt[n * 16 + p + 1] = pack_bf16_rne(Wb[(2 * p + 2) * 32 + n], Wb[(2 * p + 3) * 32 + n]);
    }
    __syncthreads();

    const int l = tid & 63;
    const int w = tid >> 6;
    const int half = l >> 5;
    const int ln = l & 31;
    const uint4* wbtv = reinterpret_cast<const uint4*>(wbt);
    const uint4 bu0 = wbtv[ln * 4 + half];
    const uint4 bu1 = wbtv[ln * 4 + half + 2];
    const float bbn = bb[ln];
    const uint4* hidv = reinterpret_cast<const uint4*>(hidb);

    for (int cb = 0; cb < M; cb += BS) {
        if (cb > 0) __syncthreads();  // prior A-reads done before overwrite
        const int kk = min(cb + tid, M - 1);
        const int2 ed = sedgeB[base + kk];
        sdst[tid] = ed.y & 127;
        {
            const float4* Up = U + (size_t)ed.x * 8;
            const float4* Vp = V + (size_t)ed.y * 8;
#pragma unroll
            for (int q = 0; q < 8; ++q) {
                const float4 a = Up[q];
                const float4 b = Vp[q];
                const float h0 = fmaxf(a.x - b.x, 0.0f);
                const float h1 = fmaxf(a.y - b.y, 0.0f);
                const float h2 = fmaxf(a.z - b.z, 0.0f);
                const float h3 = fmaxf(a.w - b.w, 0.0f);
                hidb[tid * 20 + 2 * q + 0] = pack_bf16_rne(h0, h1);
                hidb[tid * 20 + 2 * q + 1] = pack_bf16_rne(h2, h3);
            }
        }
        __syncthreads();

        const int e0 = 64 * w + ln;
        const int e1 = e0 + 32;
        const uint4 au00 = hidv[e0 * 5 + half];
        const uint4 au01 = hidv[e0 * 5 + half + 2];
        const uint4 au10 = hidv[e1 * 5 + half];
        const uint4 au11 = hidv[e1 * 5 + half + 2];

        f32x16 c0 = {};
        f32x16 c1 = {};
        c0 = __builtin_amdgcn_mfma_f32_32x32x16_bf16(__builtin_bit_cast(bf16x8, au00),
                                                     __builtin_bit_cast(bf16x8, bu0), c0, 0, 0,
                                                     0);
        c0 = __builtin_amdgcn_mfma_f32_32x32x16_bf16(__builtin_bit_cast(bf16x8, au01),
                                                     __builtin_bit_cast(bf16x8, bu1), c0, 0, 0,
                                                     0);
        c1 = __builtin_amdgcn_mfma_f32_32x32x16_bf16(__builtin_bit_cast(bf16x8, au10),
                                                     __builtin_bit_cast(bf16x8, bu0), c1, 0, 0,
                                                     0);
        c1 = __builtin_amdgcn_mfma_f32_32x32x16_bf16(__builtin_bit_cast(bf16x8, au11),
                                                     __builtin_bit_cast(bf16x8, bu1), c1, 0, 0,
                                                     0);

        // C layout: col(n)=ln, row(edge within chunk) = (r&3)+8*(r>>2)+4*half
#pragma unroll
        for (int rr = 0; rr < 16; ++rr) {
            const int row = (rr & 3) + 8 * (rr >> 2) + 4 * half;
            const int er = 64 * w + row;
            const int da = sdst[er];
            const int db = sdst[er + 32];
            atomicMax(&sagg[da * 32 + ln], ordenc(c0[rr] + bbn));
            atomicMax(&sagg[db * 32 + ln], ordenc(c1[rr] + bbn));
        }
    }
    __syncthreads();

    // coalesced relu'd write of the range's 128 nodes
    const int nodeBase = r * 128;
    for (int idx = tid; idx < 4096; idx += BS) {
        const int node = nodeBase + (idx >> 5);
        if (node < N) out[(size_t)node * 32 + (idx & 31)] = fmaxf(orddec(sagg[idx]), 0.0f);
    }
}

extern "C" void kernel_launch(void* const* d_in, const int* in_sizes, int n_in,
                              void* d_out, int out_size, void* d_ws, size_t ws_size,
                              hipStream_t stream) {
    const float* pos = (const float*)d_in[0];
    const int* ei = (const int*)d_in[1];
    const float* W1 = (const float*)d_in[3];
    const float* b1 = (const float*)d_in[4];
    const float* W2 = (const float*)d_in[5];
    const float* b2 = (const float*)d_in[6];
    const float* W3 = (const float*)d_in[7];
    const float* b3 = (const float*)d_in[8];
    const float* W4 = (const float*)d_in[9];
    const float* b4 = (const float*)d_in[10];

    const int E = in_sizes[1] / 2;
    const int N = in_sizes[0] / 3;
    const int n32 = N * 32;
    const int NR = (N + 127) / 128;         // ranges of 128 dsts
    const int NRP = ((NR + 15) / 16) * 16;  // padded (<= 1024)
    const int NB1 = (E + K1_EDGES - 1) / K1_EDGES;
    const int BH = NB1 * NRP;

    int* blockHist = (int*)d_ws;               // BH
    int* off = blockHist + BH;                 // BH
    int* total = off + BH;                     // NRP
    int* rangeBase = total + NRP;              // NRP  (BH,NRP even -> int2 align ok)
    int2* sedgeB = (int2*)(rangeBase + NRP);   // E
    float* h1 = (float*)(sedgeB + E);          // n32 (16B-aligned)
    float* Ubuf = h1 + n32;                    // n32
    float* Vbuf = Ubuf + n32;                  // n32

    const int NBn = (N + BS - 1) / BS;

    // --- bucket the edges by 128-dst range (no within-range sort needed) ---
    bucket_hist_kernel<<<NB1, BS, 0, stream>>>(ei, E, NRP, blockHist);
    off_scan_kernel<<<(NRP * 64 + 511) / 512, 512, 0, stream>>>(blockHist, NB1, NRP, off,
                                                                total);
    range_scan_kernel<<<1, 1024, 0, stream>>>(total, NRP, rangeBase);
    bucket_scatter_kernel<<<NB1, BS, 0, stream>>>(ei, E, NRP, off, rangeBase, sedgeB);

    // --- layer 1 ---
    prep1_kernel<<<NBn, BS, 0, stream>>>(pos, W1, b1, Ubuf, Vbuf, N);
    edge_range_kernel<<<NR, BS, 0, stream>>>((const float4*)Ubuf, (const float4*)Vbuf, sedgeB,
                                             rangeBase, total, W2, b2, h1, N);
    // --- layer 2 ---
    prep2_kernel<<<NBn, BS, 0, stream>>>(pos, h1, W3, b3, Ubuf, Vbuf, N);
    edge_range_kernel<<<NR, BS, 0, stream>>>((const float4*)Ubuf, (const float4*)Vbuf, sedgeB,
                                             rangeBase, total, W4, b4, (float*)d_out, N);
}

// Round 12
// 314.634 us; speedup vs baseline: 1.0216x; 1.0216x over previous
//
#include <hip/hip_runtime.h>
#include <stdint.h>

// PointNet EdgeConv, 2 layers. Round 12.
// R8:  MLP2 via v_mfma_f32_32x32x16_bf16.                      331 us
// R10: atomic-free bucket sort.                                278 us  <- prior best
// R11: range-resident LDS aggregation (deleted bucket_sort/init/finalize)
//      but edge kernel grid-starved: 782 blocks x 4 waves, occupancy 21%,
//      gather latency exposed. 92 us/edge-kernel.              321 us
// R12: R11 pipeline + 512-thread edge blocks (8 waves, 512-edge chunks,
//      2 blocks/CU -> 16 waves/CU, half the barriers). Everything else same.

#define BS 256
#define EBS 512        // edge_range block size
#define K1_EDGES 4096  // edges staged per block in scatter pass

typedef float v2f __attribute__((ext_vector_type(2)));
typedef __attribute__((ext_vector_type(8))) short bf16x8;
typedef __attribute__((ext_vector_type(16))) float f32x16;

__device__ __forceinline__ unsigned ordenc(float f) {
    unsigned u = __float_as_uint(f);
    return (u & 0x80000000u) ? ~u : (u | 0x80000000u);
}
__device__ __forceinline__ float orddec(unsigned o) {
    unsigned u = (o & 0x80000000u) ? (o ^ 0x80000000u) : ~o;
    return __uint_as_float(u);
}
#define ORD_NEG_INF 0x007FFFFFu  // ordenc(-inf)

__device__ __forceinline__ unsigned pack_bf16_rne(float x, float y) {
    unsigned ux = __float_as_uint(x), uy = __float_as_uint(y);
    ux = ux + 0x7FFFu + ((ux >> 16) & 1u);
    uy = uy + 0x7FFFu + ((uy >> 16) & 1u);
    return (ux >> 16) | (uy & 0xFFFF0000u);
}

// ---------------- pass 1a: per-block range histogram (LDS only) -------------
__global__ __launch_bounds__(BS) void bucket_hist_kernel(const int* __restrict__ ei, int E,
                                                         int NRP, int* __restrict__ blockHist) {
    __shared__ int hist[1024];
    const int tid = threadIdx.x;
    for (int r = tid; r < 1024; r += BS) hist[r] = 0;
    __syncthreads();
    const int base = blockIdx.x * K1_EDGES;
    const int M = min(K1_EDGES, E - base);
    for (int i = tid; i < M; i += BS) atomicAdd(&hist[ei[E + base + i] >> 7], 1);
    __syncthreads();
    for (int r = tid; r < NRP; r += BS) blockHist[blockIdx.x * NRP + r] = hist[r];
}

// ---------------- pass 2a: per-(block,range) LOCAL prefixes + range totals --
__global__ __launch_bounds__(512) void off_scan_kernel(const int* __restrict__ blockHist,
                                                       int NB1, int NRP,
                                                       int* __restrict__ off,
                                                       int* __restrict__ total) {
    const int r = (blockIdx.x * 512 + threadIdx.x) >> 6;
    const int lane = threadIdx.x & 63;
    if (r >= NRP) return;
    int carry = 0;
    const int chunks = (NB1 + 63) / 64;
    for (int c = 0; c < chunks; ++c) {
        const int b = c * 64 + lane;
        const int v = (b < NB1) ? blockHist[b * NRP + r] : 0;
        int x = v;
#pragma unroll
        for (int d = 1; d < 64; d <<= 1) {
            int y = __shfl_up(x, d, 64);
            if (lane >= d) x += y;
        }
        if (b < NB1) off[b * NRP + r] = carry + (x - v);
        carry += __shfl(x, 63, 64);
    }
    if (lane == 0) total[r] = carry;
}

// ---------------- pass 2b: exclusive scan of totals -> rangeBase ------------
__global__ __launch_bounds__(1024) void range_scan_kernel(const int* __restrict__ total,
                                                          int NRP, int* __restrict__ rangeBase) {
    __shared__ int s[1024];
    const int t = threadIdx.x;
    const int v = (t < NRP) ? total[t] : 0;
    s[t] = v;
    __syncthreads();
    for (int off = 1; off < 1024; off <<= 1) {
        int add = (t >= off) ? s[t - off] : 0;
        __syncthreads();
        s[t] += add;
        __syncthreads();
    }
    if (t < NRP) rangeBase[t] = s[t] - v;
}

// ---------------- pass 1b: LDS-ranked scatter into range buckets ------------
__global__ __launch_bounds__(BS) void bucket_scatter_kernel(
    const int* __restrict__ ei, int E, int NRP, const int* __restrict__ off,
    const int* __restrict__ rangeBase, int2* __restrict__ sedgeB) {
    __shared__ int2 stage[K1_EDGES];          // 32 KB
    __shared__ unsigned short inv[K1_EDGES];  // 8 KB
    __shared__ int hist[1024], start[1024], cursor[1024];
    __shared__ int ts[BS];
    const int tid = threadIdx.x;
    for (int r = tid; r < 1024; r += BS) hist[r] = 0;
    __syncthreads();
    const int base = blockIdx.x * K1_EDGES;
    const int M = min(K1_EDGES, E - base);
    for (int i = tid; i < M; i += BS) {
        const int2 p = make_int2(ei[base + i], ei[E + base + i]);
        stage[i] = p;
        atomicAdd(&hist[p.y >> 7], 1);
    }
    __syncthreads();
    {
        const int i0 = tid * 4;
        const int l0 = hist[i0], l1 = hist[i0 + 1], l2 = hist[i0 + 2], l3 = hist[i0 + 3];
        const int tsum = l0 + l1 + l2 + l3;
        ts[tid] = tsum;
        __syncthreads();
        for (int off2 = 1; off2 < BS; off2 <<= 1) {
            int add = (tid >= off2) ? ts[tid - off2] : 0;
            __syncthreads();
            ts[tid] += add;
            __syncthreads();
        }
        const int texcl = ts[tid] - tsum;
        start[i0] = texcl;
        start[i0 + 1] = texcl + l0;
        start[i0 + 2] = texcl + l0 + l1;
        start[i0 + 3] = texcl + l0 + l1 + l2;
        cursor[i0] = start[i0];
        cursor[i0 + 1] = start[i0 + 1];
        cursor[i0 + 2] = start[i0 + 2];
        cursor[i0 + 3] = start[i0 + 3];
    }
    __syncthreads();
    for (int i = tid; i < M; i += BS) {
        const int pos = atomicAdd(&cursor[stage[i].y >> 7], 1);
        inv[pos] = (unsigned short)i;
    }
    __syncthreads();
    const int* offb = off + blockIdx.x * NRP;
    for (int j = tid; j < M; j += BS) {
        const int2 p = stage[inv[j]];
        const int r = p.y >> 7;
        sedgeB[rangeBase[r] + offb[r] + (j - start[r])] = p;  // contiguous runs
    }
}

// ---------------- per-node U/V precompute ----------------
__global__ __launch_bounds__(BS) void prep1_kernel(const float* __restrict__ pos,
                                                   const float* __restrict__ Wa,
                                                   const float* __restrict__ ba,
                                                   float* __restrict__ U, float* __restrict__ V,
                                                   int N) {
    int n = blockIdx.x * BS + threadIdx.x;
    if (n >= N) return;
    const float p[3] = {pos[3 * n], pos[3 * n + 1], pos[3 * n + 2]};
    v2f u[16], v[16];
#pragma unroll
    for (int g = 0; g < 16; ++g) {
        u[g] = *reinterpret_cast<const v2f*>(&ba[g * 2]);
        v2f z = {0.0f, 0.0f};
        v[g] = z;
    }
#pragma unroll
    for (int i = 0; i < 3; ++i) {
        const v2f f = {p[i], p[i]};
#pragma unroll
        for (int g = 0; g < 16; ++g) {
            const v2f wA = *reinterpret_cast<const v2f*>(&Wa[i * 32 + g * 2]);
            const v2f wB = *reinterpret_cast<const v2f*>(&Wa[(i + 3) * 32 + g * 2]);
            u[g] = __builtin_elementwise_fma(f, wA + wB, u[g]);
            v[g] = __builtin_elementwise_fma(f, wB, v[g]);
        }
    }
    float4* Up = reinterpret_cast<float4*>(U + (size_t)n * 32);
    float4* Vp = reinterpret_cast<float4*>(V + (size_t)n * 32);
#pragma unroll
    for (int q = 0; q < 8; ++q) {
        Up[q] = make_float4(u[2 * q].x, u[2 * q].y, u[2 * q + 1].x, u[2 * q + 1].y);
        Vp[q] = make_float4(v[2 * q].x, v[2 * q].y, v[2 * q + 1].x, v[2 * q + 1].y);
    }
}

__global__ __launch_bounds__(BS) void prep2_kernel(const float* __restrict__ pos,
                                                   const float* __restrict__ h1,
                                                   const float* __restrict__ Wa,
                                                   const float* __restrict__ ba,
                                                   float* __restrict__ U, float* __restrict__ V,
                                                   int N) {
    int n = blockIdx.x * BS + threadIdx.x;
    if (n >= N) return;
    float h[32];
    const float4* hp = reinterpret_cast<const float4*>(h1 + (size_t)n * 32);
#pragma unroll
    for (int q = 0; q < 8; ++q) {
        float4 t = hp[q];
        h[4 * q + 0] = t.x;
        h[4 * q + 1] = t.y;
        h[4 * q + 2] = t.z;
        h[4 * q + 3] = t.w;
    }
    const float p[3] = {pos[3 * n], pos[3 * n + 1], pos[3 * n + 2]};
    v2f u[16], v[16];
#pragma unroll
    for (int g = 0; g < 16; ++g) {
        u[g] = *reinterpret_cast<const v2f*>(&ba[g * 2]);
        v2f z = {0.0f, 0.0f};
        v[g] = z;
    }
#pragma unroll
    for (int i = 0; i < 32; ++i) {
        const v2f f = {h[i], h[i]};
#pragma unroll
        for (int g = 0; g < 16; ++g) {
            const v2f w = *reinterpret_cast<const v2f*>(&Wa[i * 32 + g * 2]);
            u[g] = __builtin_elementwise_fma(f, w, u[g]);
        }
    }
#pragma unroll
    for (int i = 0; i < 3; ++i) {
        const v2f f = {p[i], p[i]};
#pragma unroll
        for (int g = 0; g < 16; ++g) {
            const v2f w = *reinterpret_cast<const v2f*>(&Wa[(32 + i) * 32 + g * 2]);
            u[g] = __builtin_elementwise_fma(f, w, u[g]);
            v[g] = __builtin_elementwise_fma(f, w, v[g]);
        }
    }
    float4* Up = reinterpret_cast<float4*>(U + (size_t)n * 32);
    float4* Vp = reinterpret_cast<float4*>(V + (size_t)n * 32);
#pragma unroll
    for (int q = 0; q < 8; ++q) {
        Up[q] = make_float4(u[2 * q].x, u[2 * q].y, u[2 * q + 1].x, u[2 * q + 1].y);
        Vp[q] = make_float4(v[2 * q].x, v[2 * q].y, v[2 * q + 1].x, v[2 * q + 1].y);
    }
}

// ---------------- range-resident edge kernel (512 threads) ----------------
// One block per 128-dst range. LDS (61440 B, 2 blocks/CU, 16 waves/CU):
//   hidb [512*20] dwords : hid bf16 pairs, stride 20 (A-fragment layout)
//   wbt  [512]    dwords : Wb^T bf16 pairs (B fragments)
//   sagg [128*32] dwords : ord-encoded running max
//   sdst [512]    ints   : dst&127 per staged edge
// Chunks of 512 edges: gather U/V -> hid -> MFMA -> ds_max_u32 from C regs.
__global__ __launch_bounds__(EBS, 2) void edge_range_kernel(
    const float4* __restrict__ U, const float4* __restrict__ V,
    const int2* __restrict__ sedgeB, const int* __restrict__ rangeBase,
    const int* __restrict__ total, const float* __restrict__ Wb,
    const float* __restrict__ bb, float* __restrict__ out, int N) {
    __shared__ __align__(16) unsigned hidb[EBS * 20];
    __shared__ __align__(16) unsigned wbt[512];
    __shared__ unsigned sagg[128 * 32];
    __shared__ int sdst[EBS];

    const int r = blockIdx.x;
    const int tid = threadIdx.x;
    const int base = rangeBase[r];
    const int M = total[r];

    for (int i = tid; i < 4096; i += EBS) sagg[i] = ORD_NEG_INF;
    if (tid < 256) {
        const int n = tid & 31;
        const int p = (tid >> 5) * 2;
        wbt[n * 16 + p + 0] = pack_bf16_rne(Wb[(2 * p + 0) * 32 + n], Wb[(2 * p + 1) * 32 + n]);
        wbt[n * 16 + p + 1] = pack_bf16_rne(Wb[(2 * p + 2) * 32 + n], Wb[(2 * p + 3) * 32 + n]);
    }
    __syncthreads();

    const int l = tid & 63;
    const int w = tid >> 6;  // 0..7
    const int half = l >> 5;
    const int ln = l & 31;
    const uint4* wbtv = reinterpret_cast<const uint4*>(wbt);
    const uint4 bu0 = wbtv[ln * 4 + half];
    const uint4 bu1 = wbtv[ln * 4 + half + 2];
    const float bbn = bb[ln];
    const uint4* hidv = reinterpret_cast<const uint4*>(hidb);

    for (int cb = 0; cb < M; cb += EBS) {
        if (cb > 0) __syncthreads();  // prior A/sdst reads done before overwrite
        const int kk = min(cb + tid, M - 1);
        const int2 ed = sedgeB[base + kk];
        sdst[tid] = ed.y & 127;
        {
            const float4* Up = U + (size_t)ed.x * 8;
            const float4* Vp = V + (size_t)ed.y * 8;
#pragma unroll
            for (int q = 0; q < 8; ++q) {
                const float4 a = Up[q];
                const float4 b = Vp[q];
                const float h0 = fmaxf(a.x - b.x, 0.0f);
                const float h1 = fmaxf(a.y - b.y, 0.0f);
                const float h2 = fmaxf(a.z - b.z, 0.0f);
                const float h3 = fmaxf(a.w - b.w, 0.0f);
                hidb[tid * 20 + 2 * q + 0] = pack_bf16_rne(h0, h1);
                hidb[tid * 20 + 2 * q + 1] = pack_bf16_rne(h2, h3);
            }
        }
        __syncthreads();

        const int e0 = 64 * w + ln;  // covers 0..511
        const int e1 = e0 + 32;
        const uint4 au00 = hidv[e0 * 5 + half];
        const uint4 au01 = hidv[e0 * 5 + half + 2];
        const uint4 au10 = hidv[e1 * 5 + half];
        const uint4 au11 = hidv[e1 * 5 + half + 2];

        f32x16 c0 = {};
        f32x16 c1 = {};
        c0 = __builtin_amdgcn_mfma_f32_32x32x16_bf16(__builtin_bit_cast(bf16x8, au00),
                                                     __builtin_bit_cast(bf16x8, bu0), c0, 0, 0,
                                                     0);
        c0 = __builtin_amdgcn_mfma_f32_32x32x16_bf16(__builtin_bit_cast(bf16x8, au01),
                                                     __builtin_bit_cast(bf16x8, bu1), c0, 0, 0,
                                                     0);
        c1 = __builtin_amdgcn_mfma_f32_32x32x16_bf16(__builtin_bit_cast(bf16x8, au10),
                                                     __builtin_bit_cast(bf16x8, bu0), c1, 0, 0,
                                                     0);
        c1 = __builtin_amdgcn_mfma_f32_32x32x16_bf16(__builtin_bit_cast(bf16x8, au11),
                                                     __builtin_bit_cast(bf16x8, bu1), c1, 0, 0,
                                                     0);

        // C layout: col(n)=ln, row(edge within chunk) = (rr&3)+8*(rr>>2)+4*half
#pragma unroll
        for (int rr = 0; rr < 16; ++rr) {
            const int row = (rr & 3) + 8 * (rr >> 2) + 4 * half;
            const int er = 64 * w + row;
            const int da = sdst[er];
            const int db = sdst[er + 32];
            atomicMax(&sagg[da * 32 + ln], ordenc(c0[rr] + bbn));
            atomicMax(&sagg[db * 32 + ln], ordenc(c1[rr] + bbn));
        }
    }
    __syncthreads();

    // coalesced relu'd write of the range's 128 nodes
    const int nodeBase = r * 128;
    for (int idx = tid; idx < 4096; idx += EBS) {
        const int node = nodeBase + (idx >> 5);
        if (node < N) out[(size_t)node * 32 + (idx & 31)] = fmaxf(orddec(sagg[idx]), 0.0f);
    }
}

extern "C" void kernel_launch(void* const* d_in, const int* in_sizes, int n_in,
                              void* d_out, int out_size, void* d_ws, size_t ws_size,
                              hipStream_t stream) {
    const float* pos = (const float*)d_in[0];
    const int* ei = (const int*)d_in[1];
    const float* W1 = (const float*)d_in[3];
    const float* b1 = (const float*)d_in[4];
    const float* W2 = (const float*)d_in[5];
    const float* b2 = (const float*)d_in[6];
    const float* W3 = (const float*)d_in[7];
    const float* b3 = (const float*)d_in[8];
    const float* W4 = (const float*)d_in[9];
    const float* b4 = (const float*)d_in[10];

    const int E = in_sizes[1] / 2;
    const int N = in_sizes[0] / 3;
    const int n32 = N * 32;
    const int NR = (N + 127) / 128;         // ranges of 128 dsts
    const int NRP = ((NR + 15) / 16) * 16;  // padded (<= 1024)
    const int NB1 = (E + K1_EDGES - 1) / K1_EDGES;
    const int BH = NB1 * NRP;

    int* blockHist = (int*)d_ws;              // BH
    int* off = blockHist + BH;                // BH
    int* total = off + BH;                    // NRP
    int* rangeBase = total + NRP;             // NRP
    int2* sedgeB = (int2*)(rangeBase + NRP);  // E
    float* h1 = (float*)(sedgeB + E);         // n32 (16B-aligned)
    float* Ubuf = h1 + n32;                   // n32
    float* Vbuf = Ubuf + n32;                 // n32

    const int NBn = (N + BS - 1) / BS;

    // --- bucket the edges by 128-dst range (no within-range sort needed) ---
    bucket_hist_kernel<<<NB1, BS, 0, stream>>>(ei, E, NRP, blockHist);
    off_scan_kernel<<<(NRP * 64 + 511) / 512, 512, 0, stream>>>(blockHist, NB1, NRP, off,
                                                                total);
    range_scan_kernel<<<1, 1024, 0, stream>>>(total, NRP, rangeBase);
    bucket_scatter_kernel<<<NB1, BS, 0, stream>>>(ei, E, NRP, off, rangeBase, sedgeB);

    // --- layer 1 ---
    prep1_kernel<<<NBn, BS, 0, stream>>>(pos, W1, b1, Ubuf, Vbuf, N);
    edge_range_kernel<<<NR, EBS, 0, stream>>>((const float4*)Ubuf, (const float4*)Vbuf, sedgeB,
                                              rangeBase, total, W2, b2, h1, N);
    // --- layer 2 ---
    prep2_kernel<<<NBn, BS, 0, stream>>>(pos, h1, W3, b3, Ubuf, Vbuf, N);
    edge_range_kernel<<<NR, EBS, 0, stream>>>((const float4*)Ubuf, (const float4*)Vbuf, sedgeB,
                                              rangeBase, total, W4, b4, (float*)d_out, N);
}

// Round 13
// 256.928 us; speedup vs baseline: 1.2511x; 1.2246x over previous
//
#include <hip/hip_runtime.h>
#include <stdint.h>

// PointNet EdgeConv, 2 layers. Round 13.
// R8:  MLP2 via v_mfma_f32_32x32x16_bf16.                      331 us
// R10: atomic-free bucket sort + MFMA edge_seg.                278 us <- best
// R11: range-resident LDS agg: grid-starved (782 blocks).      321 us
// R12: 512-thread ranges: grid quantization, still starved.    315 us
// R13: REVERT to R10 structure wholesale; U table stored as packed bf16
//      (12.8 -> 6.4 MB, per-edge random gather 128 -> 64 B) to cut the
//      L2-miss traffic that bounds edge_seg. V stays f32 (block-local dst,
//      cache-friendly; limits added rounding).

#define BS 256
#define K1_EDGES 4096  // edges staged per block in scatter pass
#define P2_CAP 3072    // max edges per 128-dst range bucket (mean 2048, +22 sigma)

typedef float v2f __attribute__((ext_vector_type(2)));
typedef __attribute__((ext_vector_type(8))) short bf16x8;
typedef __attribute__((ext_vector_type(16))) float f32x16;

__device__ __forceinline__ unsigned ordenc(float f) {
    unsigned u = __float_as_uint(f);
    return (u & 0x80000000u) ? ~u : (u | 0x80000000u);
}
__device__ __forceinline__ float orddec(unsigned o) {
    unsigned u = (o & 0x80000000u) ? (o ^ 0x80000000u) : ~o;
    return __uint_as_float(u);
}
#define ORD_NEG_INF 0x007FFFFFu  // ordenc(-inf)

__device__ __forceinline__ unsigned pack_bf16_rne(float x, float y) {
    unsigned ux = __float_as_uint(x), uy = __float_as_uint(y);
    ux = ux + 0x7FFFu + ((ux >> 16) & 1u);
    uy = uy + 0x7FFFu + ((uy >> 16) & 1u);
    return (ux >> 16) | (uy & 0xFFFF0000u);
}

// ---------------- utility kernels ----------------

__global__ __launch_bounds__(BS) void init_kernel(unsigned* __restrict__ a,
                                                  unsigned* __restrict__ b, int n32) {
    int i = blockIdx.x * BS + threadIdx.x;
    if (i < n32) {
        a[i] = ORD_NEG_INF;
        b[i] = ORD_NEG_INF;
    }
}

__global__ __launch_bounds__(BS) void finalize_kernel(unsigned* __restrict__ buf, int n) {
    int i = blockIdx.x * BS + threadIdx.x;
    if (i < n) {
        float v = orddec(buf[i]);
        reinterpret_cast<float*>(buf)[i] = fmaxf(v, 0.0f);
    }
}

// ---------------- pass 1a: per-block range histogram (LDS only) -------------
__global__ __launch_bounds__(BS) void bucket_hist_kernel(const int* __restrict__ ei, int E,
                                                         int NRP, int* __restrict__ blockHist) {
    __shared__ int hist[1024];
    const int tid = threadIdx.x;
    for (int r = tid; r < 1024; r += BS) hist[r] = 0;
    __syncthreads();
    const int base = blockIdx.x * K1_EDGES;
    const int M = min(K1_EDGES, E - base);
    for (int i = tid; i < M; i += BS) atomicAdd(&hist[ei[E + base + i] >> 7], 1);
    __syncthreads();
    for (int r = tid; r < NRP; r += BS) blockHist[blockIdx.x * NRP + r] = hist[r];
}

// ---------------- pass 2a: per-(block,range) LOCAL prefixes + range totals --
__global__ __launch_bounds__(512) void off_scan_kernel(const int* __restrict__ blockHist,
                                                       int NB1, int NRP,
                                                       int* __restrict__ off,
                                                       int* __restrict__ total) {
    const int r = (blockIdx.x * 512 + threadIdx.x) >> 6;
    const int lane = threadIdx.x & 63;
    if (r >= NRP) return;
    int carry = 0;
    const int chunks = (NB1 + 63) / 64;
    for (int c = 0; c < chunks; ++c) {
        const int b = c * 64 + lane;
        const int v = (b < NB1) ? blockHist[b * NRP + r] : 0;
        int x = v;
#pragma unroll
        for (int d = 1; d < 64; d <<= 1) {
            int y = __shfl_up(x, d, 64);
            if (lane >= d) x += y;
        }
        if (b < NB1) off[b * NRP + r] = carry + (x - v);
        carry += __shfl(x, 63, 64);
    }
    if (lane == 0) total[r] = carry;
}

// ---------------- pass 2b: exclusive scan of totals -> rangeBase ------------
__global__ __launch_bounds__(1024) void range_scan_kernel(const int* __restrict__ total,
                                                          int NRP, int* __restrict__ rangeBase) {
    __shared__ int s[1024];
    const int t = threadIdx.x;
    const int v = (t < NRP) ? total[t] : 0;
    s[t] = v;
    __syncthreads();
    for (int off = 1; off < 1024; off <<= 1) {
        int add = (t >= off) ? s[t - off] : 0;
        __syncthreads();
        s[t] += add;
        __syncthreads();
    }
    if (t < NRP) rangeBase[t] = s[t] - v;
}

// ---------------- pass 1b: LDS-ranked scatter into range buckets ------------
__global__ __launch_bounds__(BS) void bucket_scatter_kernel(
    const int* __restrict__ ei, int E, int NRP, const int* __restrict__ off,
    const int* __restrict__ rangeBase, int2* __restrict__ sedgeB) {
    __shared__ int2 stage[K1_EDGES];          // 32 KB
    __shared__ unsigned short inv[K1_EDGES];  // 8 KB
    __shared__ int hist[1024], start[1024], cursor[1024];
    __shared__ int ts[BS];
    const int tid = threadIdx.x;
    for (int r = tid; r < 1024; r += BS) hist[r] = 0;
    __syncthreads();
    const int base = blockIdx.x * K1_EDGES;
    const int M = min(K1_EDGES, E - base);
    for (int i = tid; i < M; i += BS) {
        const int2 p = make_int2(ei[base + i], ei[E + base + i]);
        stage[i] = p;
        atomicAdd(&hist[p.y >> 7], 1);
    }
    __syncthreads();
    {
        const int i0 = tid * 4;
        const int l0 = hist[i0], l1 = hist[i0 + 1], l2 = hist[i0 + 2], l3 = hist[i0 + 3];
        const int tsum = l0 + l1 + l2 + l3;
        ts[tid] = tsum;
        __syncthreads();
        for (int off2 = 1; off2 < BS; off2 <<= 1) {
            int add = (tid >= off2) ? ts[tid - off2] : 0;
            __syncthreads();
            ts[tid] += add;
            __syncthreads();
        }
        const int texcl = ts[tid] - tsum;
        start[i0] = texcl;
        start[i0 + 1] = texcl + l0;
        start[i0 + 2] = texcl + l0 + l1;
        start[i0 + 3] = texcl + l0 + l1 + l2;
        cursor[i0] = start[i0];
        cursor[i0 + 1] = start[i0 + 1];
        cursor[i0 + 2] = start[i0 + 2];
        cursor[i0 + 3] = start[i0 + 3];
    }
    __syncthreads();
    for (int i = tid; i < M; i += BS) {
        const int pos = atomicAdd(&cursor[stage[i].y >> 7], 1);
        inv[pos] = (unsigned short)i;
    }
    __syncthreads();
    const int* offb = off + blockIdx.x * NRP;
    for (int j = tid; j < M; j += BS) {
        const int2 p = stage[inv[j]];
        const int r = p.y >> 7;
        sedgeB[rangeBase[r] + offb[r] + (j - start[r])] = p;  // contiguous runs
    }
}

// ---------------- pass 3: in-LDS sort within each range bucket --------------
__global__ __launch_bounds__(BS) void bucket_sort_kernel(
    const int2* __restrict__ sedgeB, const int* __restrict__ rangeBase,
    const int* __restrict__ total, int N, int2* __restrict__ sedge, int* __restrict__ row_ptr,
    int* __restrict__ cnt) {
    __shared__ int2 stage[P2_CAP];
    __shared__ unsigned short inv[P2_CAP];
    __shared__ int hist[128], start[128], cursor[128];
    const int r = blockIdx.x;
    const int tid = threadIdx.x;
    const int base = rangeBase[r];
    const int M = total[r];
    const bool fast = (M <= P2_CAP);
    if (tid < 128) hist[tid] = 0;
    __syncthreads();
    if (fast) {
        for (int i = tid; i < M; i += BS) {
            const int2 p = sedgeB[base + i];
            stage[i] = p;
            atomicAdd(&hist[p.y & 127], 1);
        }
    } else {  // statistically never; correct slow path
        if (tid < 128) {
            int c = 0;
            for (int i = 0; i < M; ++i) c += ((sedgeB[base + i].y & 127) == tid);
            hist[tid] = c;
        }
    }
    __syncthreads();
    if (tid < 128) start[tid] = hist[tid];
    __syncthreads();
    for (int off2 = 1; off2 < 128; off2 <<= 1) {
        int add = 0;
        if (tid < 128 && tid >= off2) add = start[tid - off2];
        __syncthreads();
        if (tid < 128) start[tid] += add;
        __syncthreads();
    }
    if (tid < 128) {
        const int excl = start[tid] - hist[tid];
        start[tid] = excl;
        cursor[tid] = excl;
        const int node = r * 128 + tid;
        if (node < N) {
            row_ptr[node] = base + excl;
            cnt[node] = hist[tid];
        }
    }
    __syncthreads();
    if (fast) {
        for (int i = tid; i < M; i += BS) {
            const int pos = atomicAdd(&cursor[stage[i].y & 127], 1);
            inv[pos] = (unsigned short)i;
        }
        __syncthreads();
        for (int j = tid; j < M; j += BS) sedge[base + j] = stage[inv[j]];
    } else {
        if (tid < 128) {
            int c = base + start[tid];
            for (int i = 0; i < M; ++i) {
                const int2 p = sedgeB[base + i];
                if ((p.y & 127) == tid) sedge[c++] = p;
            }
        }
    }
}

// ---------------- per-node U/V precompute (U packed bf16, V f32) ------------
__global__ __launch_bounds__(BS) void prep1_kernel(const float* __restrict__ pos,
                                                   const float* __restrict__ Wa,
                                                   const float* __restrict__ ba,
                                                   unsigned* __restrict__ Ubf,
                                                   float* __restrict__ V, int N) {
    int n = blockIdx.x * BS + threadIdx.x;
    if (n >= N) return;
    const float p[3] = {pos[3 * n], pos[3 * n + 1], pos[3 * n + 2]};
    v2f u[16], v[16];
#pragma unroll
    for (int g = 0; g < 16; ++g) {
        u[g] = *reinterpret_cast<const v2f*>(&ba[g * 2]);
        v2f z = {0.0f, 0.0f};
        v[g] = z;
    }
#pragma unroll
    for (int i = 0; i < 3; ++i) {
        const v2f f = {p[i], p[i]};
#pragma unroll
        for (int g = 0; g < 16; ++g) {
            const v2f wA = *reinterpret_cast<const v2f*>(&Wa[i * 32 + g * 2]);
            const v2f wB = *reinterpret_cast<const v2f*>(&Wa[(i + 3) * 32 + g * 2]);
            u[g] = __builtin_elementwise_fma(f, wA + wB, u[g]);
            v[g] = __builtin_elementwise_fma(f, wB, v[g]);
        }
    }
    uint4* Up = reinterpret_cast<uint4*>(Ubf + (size_t)n * 16);
    float4* Vp = reinterpret_cast<float4*>(V + (size_t)n * 32);
#pragma unroll
    for (int q = 0; q < 4; ++q) {
        uint4 o;
        o.x = pack_bf16_rne(u[4 * q + 0].x, u[4 * q + 0].y);
        o.y = pack_bf16_rne(u[4 * q + 1].x, u[4 * q + 1].y);
        o.z = pack_bf16_rne(u[4 * q + 2].x, u[4 * q + 2].y);
        o.w = pack_bf16_rne(u[4 * q + 3].x, u[4 * q + 3].y);
        Up[q] = o;
    }
#pragma unroll
    for (int q = 0; q < 8; ++q)
        Vp[q] = make_float4(v[2 * q].x, v[2 * q].y, v[2 * q + 1].x, v[2 * q + 1].y);
}

// Layer 2 prep: reads layer-1 agg (ordered uint), decodes h inline.
__global__ __launch_bounds__(BS) void prep2_kernel(const float* __restrict__ pos,
                                                   const unsigned* __restrict__ aggA,
                                                   const float* __restrict__ Wa,
                                                   const float* __restrict__ ba,
                                                   unsigned* __restrict__ Ubf,
                                                   float* __restrict__ V, int N) {
    int n = blockIdx.x * BS + threadIdx.x;
    if (n >= N) return;
    float h[32];
    const uint4* hp = reinterpret_cast<const uint4*>(aggA + (size_t)n * 32);
#pragma unroll
    for (int q = 0; q < 8; ++q) {
        uint4 t = hp[q];
        h[4 * q + 0] = fmaxf(orddec(t.x), 0.0f);
        h[4 * q + 1] = fmaxf(orddec(t.y), 0.0f);
        h[4 * q + 2] = fmaxf(orddec(t.z), 0.0f);
        h[4 * q + 3] = fmaxf(orddec(t.w), 0.0f);
    }
    const float p[3] = {pos[3 * n], pos[3 * n + 1], pos[3 * n + 2]};
    v2f u[16], v[16];
#pragma unroll
    for (int g = 0; g < 16; ++g) {
        u[g] = *reinterpret_cast<const v2f*>(&ba[g * 2]);
        v2f z = {0.0f, 0.0f};
        v[g] = z;
    }
#pragma unroll
    for (int i = 0; i < 32; ++i) {
        const v2f f = {h[i], h[i]};
#pragma unroll
        for (int g = 0; g < 16; ++g) {
            const v2f w = *reinterpret_cast<const v2f*>(&Wa[i * 32 + g * 2]);
            u[g] = __builtin_elementwise_fma(f, w, u[g]);
        }
    }
#pragma unroll
    for (int i = 0; i < 3; ++i) {
        const v2f f = {p[i], p[i]};
#pragma unroll
        for (int g = 0; g < 16; ++g) {
            const v2f w = *reinterpret_cast<const v2f*>(&Wa[(32 + i) * 32 + g * 2]);
            u[g] = __builtin_elementwise_fma(f, w, u[g]);
            v[g] = __builtin_elementwise_fma(f, w, v[g]);
        }
    }
    uint4* Up = reinterpret_cast<uint4*>(Ubf + (size_t)n * 16);
    float4* Vp = reinterpret_cast<float4*>(V + (size_t)n * 32);
#pragma unroll
    for (int q = 0; q < 4; ++q) {
        uint4 o;
        o.x = pack_bf16_rne(u[4 * q + 0].x, u[4 * q + 0].y);
        o.y = pack_bf16_rne(u[4 * q + 1].x, u[4 * q + 1].y);
        o.z = pack_bf16_rne(u[4 * q + 2].x, u[4 * q + 2].y);
        o.w = pack_bf16_rne(u[4 * q + 3].x, u[4 * q + 3].y);
        Up[q] = o;
    }
#pragma unroll
    for (int q = 0; q < 8; ++q)
        Vp[q] = make_float4(v[2 * q].x, v[2 * q].y, v[2 * q + 1].x, v[2 * q + 1].y);
}

// ---------------- fused edge kernel: hid -> MFMA MLP2 -> segmented max ------
// LDS union (33792 B):
//   phase A: dwords [0, 5120)   = hid packed bf16 pairs, [edge][20] (16 used)
//            dwords [5120,5632) = Wbt bf16 pairs, [n][16]
//   phase B: floats [0, 8448)   = m matrix, sm[edge*33 + n]
__global__ __launch_bounds__(BS, 4) void edge_seg_kernel(
    const unsigned* __restrict__ Ubf, const float4* __restrict__ V,
    const int* __restrict__ row_ptr, const int* __restrict__ cnt,
    const int2* __restrict__ sedge, const float* __restrict__ Wb,
    const float* __restrict__ bb, unsigned* __restrict__ agg, int E) {
    __shared__ __align__(16) unsigned lds[8448];

    const int tid = threadIdx.x;
    const int k0 = blockIdx.x * BS;
    const int blockEnd = min(k0 + BS, E);
    const int k = min(k0 + tid, E - 1);

    // stage Wbt: bf16 pairs, Wbt[n][pair p] = {Wb[2p][n], Wb[2p+1][n]}
    {
        const int n = tid & 31;
        const int p = (tid >> 5) * 2;
        lds[5120 + n * 16 + p + 0] =
            pack_bf16_rne(Wb[(2 * p + 0) * 32 + n], Wb[(2 * p + 1) * 32 + n]);
        lds[5120 + n * 16 + p + 1] =
            pack_bf16_rne(Wb[(2 * p + 2) * 32 + n], Wb[(2 * p + 3) * 32 + n]);
    }

    const int2 ed = sedge[k];
    {
        const uint4* Up = reinterpret_cast<const uint4*>(Ubf + (size_t)ed.x * 16);
        const float4* Vp = V + (size_t)ed.y * 8;
        const uint4 U0 = Up[0];
        const uint4 U1 = Up[1];
        const uint4 U2 = Up[2];
        const uint4 U3 = Up[3];
        const unsigned uu[16] = {U0.x, U0.y, U0.z, U0.w, U1.x, U1.y, U1.z, U1.w,
                                 U2.x, U2.y, U2.z, U2.w, U3.x, U3.y, U3.z, U3.w};
#pragma unroll
        for (int q = 0; q < 8; ++q) {
            const float4 vb = Vp[q];
            const unsigned a = uu[2 * q + 0];  // channels 4q, 4q+1
            const unsigned b = uu[2 * q + 1];  // channels 4q+2, 4q+3
            const float h0 = fmaxf(__uint_as_float(a << 16) - vb.x, 0.0f);
            const float h1 = fmaxf(__uint_as_float(a & 0xFFFF0000u) - vb.y, 0.0f);
            const float h2 = fmaxf(__uint_as_float(b << 16) - vb.z, 0.0f);
            const float h3 = fmaxf(__uint_as_float(b & 0xFFFF0000u) - vb.w, 0.0f);
            lds[tid * 20 + 2 * q + 0] = pack_bf16_rne(h0, h1);
            lds[tid * 20 + 2 * q + 1] = pack_bf16_rne(h2, h3);
        }
    }
    __syncthreads();

    const int l = tid & 63;
    const int w = tid >> 6;
    const int half = l >> 5;
    const int ln = l & 31;
    const uint4* ldsv = reinterpret_cast<const uint4*>(lds);

    const int e0 = 64 * w + ln;
    const int e1 = e0 + 32;
    const uint4 au00 = ldsv[e0 * 5 + half];
    const uint4 au01 = ldsv[e0 * 5 + half + 2];
    const uint4 au10 = ldsv[e1 * 5 + half];
    const uint4 au11 = ldsv[e1 * 5 + half + 2];
    const uint4 bu0 = ldsv[1280 + ln * 4 + half];
    const uint4 bu1 = ldsv[1280 + ln * 4 + half + 2];
    const float bbn = bb[ln];
    __syncthreads();

    f32x16 c0 = {};
    f32x16 c1 = {};
    c0 = __builtin_amdgcn_mfma_f32_32x32x16_bf16(__builtin_bit_cast(bf16x8, au00),
                                                 __builtin_bit_cast(bf16x8, bu0), c0, 0, 0, 0);
    c0 = __builtin_amdgcn_mfma_f32_32x32x16_bf16(__builtin_bit_cast(bf16x8, au01),
                                                 __builtin_bit_cast(bf16x8, bu1), c0, 0, 0, 0);
    c1 = __builtin_amdgcn_mfma_f32_32x32x16_bf16(__builtin_bit_cast(bf16x8, au10),
                                                 __builtin_bit_cast(bf16x8, bu0), c1, 0, 0, 0);
    c1 = __builtin_amdgcn_mfma_f32_32x32x16_bf16(__builtin_bit_cast(bf16x8, au11),
                                                 __builtin_bit_cast(bf16x8, bu1), c1, 0, 0, 0);

    float* smf = reinterpret_cast<float*>(lds);
#pragma unroll
    for (int r = 0; r < 16; ++r) {
        const int er = 64 * w + (r & 3) + 8 * (r >> 2) + 4 * half;
        smf[er * 33 + ln] = c0[r] + bbn;
        smf[(er + 32) * 33 + ln] = c1[r] + bbn;
    }
    __syncthreads();

    const int d0 = sedge[k0].y;
    const int d1 = sedge[blockEnd - 1].y;
    const int nPairs = (d1 - d0 + 1) * 32;
    for (int idx = tid; idx < nPairs; idx += BS) {
        const int c = idx & 31;
        const int n = d0 + (idx >> 5);
        const int rs = row_ptr[n];
        const int re = rs + cnt[n];
        const int s0 = max(rs, k0);
        const int s1 = min(re, blockEnd);
        if (s0 >= s1) continue;
        float v0 = -INFINITY, v1 = -INFINITY, v2 = -INFINITY, v3 = -INFINITY;
        int e = s0;
        for (; e + 4 <= s1; e += 4) {
            float a0 = smf[(e - k0 + 0) * 33 + c];
            float a1 = smf[(e - k0 + 1) * 33 + c];
            float a2 = smf[(e - k0 + 2) * 33 + c];
            float a3 = smf[(e - k0 + 3) * 33 + c];
            v0 = fmaxf(v0, a0);
            v1 = fmaxf(v1, a1);
            v2 = fmaxf(v2, a2);
            v3 = fmaxf(v3, a3);
        }
        for (; e < s1; ++e) v0 = fmaxf(v0, smf[(e - k0) * 33 + c]);
        const float v = fmaxf(fmaxf(v0, v1), fmaxf(v2, v3));
        unsigned* p = &agg[(size_t)n * 32 + c];
        const unsigned enc = ordenc(v);
        if (rs >= k0 && re <= blockEnd)
            *p = enc;
        else
            atomicMax(p, enc);
    }
}

extern "C" void kernel_launch(void* const* d_in, const int* in_sizes, int n_in,
                              void* d_out, int out_size, void* d_ws, size_t ws_size,
                              hipStream_t stream) {
    const float* pos = (const float*)d_in[0];
    const int* ei = (const int*)d_in[1];
    const float* W1 = (const float*)d_in[3];
    const float* b1 = (const float*)d_in[4];
    const float* W2 = (const float*)d_in[5];
    const float* b2 = (const float*)d_in[6];
    const float* W3 = (const float*)d_in[7];
    const float* b3 = (const float*)d_in[8];
    const float* W4 = (const float*)d_in[9];
    const float* b4 = (const float*)d_in[10];

    const int E = in_sizes[1] / 2;
    const int N = in_sizes[0] / 3;
    const int n32 = N * 32;
    const int NPAD = ((N + BS - 1) / BS) * BS;
    const int EB = (E + BS - 1) / BS;
    const int NR = (N + 127) / 128;         // ranges of 128 dsts
    const int NRP = ((NR + 15) / 16) * 16;  // padded (<= 1024)
    const int NB1 = (E + K1_EDGES - 1) / K1_EDGES;
    const int BH = NB1 * NRP;

    int* cnt = (int*)d_ws;                    // NPAD
    int* row_ptr = cnt + NPAD;                // NPAD
    int* blockHist = row_ptr + NPAD;          // BH
    int* off = blockHist + BH;                // BH
    int* total = off + BH;                    // NRP
    int* rangeBase = total + NRP;             // NRP
    int2* sedge = (int2*)(rangeBase + NRP);   // E (offsets all mult-of-4 ints)
    unsigned* aggA = (unsigned*)(sedge + E);  // n32 (ord-encoded; prep2 decodes)
    unsigned* Ubf = aggA + n32;               // NPAD*16 (bf16-packed U)
    float* Vbuf = (float*)(Ubf + (size_t)NPAD * 16);  // n32
    int2* sedgeB = (int2*)Ubf;  // aliases Ubf+Vbuf (dead before prep1 writes)
    unsigned* aggB = (unsigned*)d_out;

    const int gridN32 = (n32 + BS - 1) / BS;
    const int NBn = (N + BS - 1) / BS;

    init_kernel<<<gridN32, BS, 0, stream>>>(aggA, aggB, n32);

    // --- atomic-free bucket sort -> sedge, row_ptr, cnt ---
    bucket_hist_kernel<<<NB1, BS, 0, stream>>>(ei, E, NRP, blockHist);
    off_scan_kernel<<<(NRP * 64 + 511) / 512, 512, 0, stream>>>(blockHist, NB1, NRP, off,
                                                                total);
    range_scan_kernel<<<1, 1024, 0, stream>>>(total, NRP, rangeBase);
    bucket_scatter_kernel<<<NB1, BS, 0, stream>>>(ei, E, NRP, off, rangeBase, sedgeB);
    bucket_sort_kernel<<<NR, BS, 0, stream>>>(sedgeB, rangeBase, total, N, sedge, row_ptr, cnt);

    // --- layer 1 ---
    prep1_kernel<<<NBn, BS, 0, stream>>>(pos, W1, b1, Ubf, Vbuf, N);
    edge_seg_kernel<<<EB, BS, 0, stream>>>(Ubf, (const float4*)Vbuf, row_ptr, cnt, sedge, W2,
                                           b2, aggA, E);
    // --- layer 2 ---
    prep2_kernel<<<NBn, BS, 0, stream>>>(pos, aggA, W3, b3, Ubf, Vbuf, N);
    edge_seg_kernel<<<EB, BS, 0, stream>>>(Ubf, (const float4*)Vbuf, row_ptr, cnt, sedge, W4,
                                           b4, aggB, E);
    finalize_kernel<<<gridN32, BS, 0, stream>>>(aggB, n32);
}

// Round 14
// 232.632 us; speedup vs baseline: 1.3818x; 1.1044x over previous
//
#include <hip/hip_runtime.h>
#include <hip/hip_bf16.h>
#include <stdint.h>

// PointNet EdgeConv, 2 layers. Round 14.
// R10: atomic-free bucket sort + MFMA edge_seg.                278 us
// R13: U table packed bf16 (random gather 128 -> 64 B).        257 us <- best
// R14: edge_seg VALU+LDS diet:
//   (a) HW v_cvt_pk_bf16_f32 via __builtin_convertvector (kills ~90 VALU/edge
//       of software RNE packing),
//   (b) m-matrix stored as bf16 edge-pairs straight from C regs (1 cvt + 1
//       ds_write per 2 edges; phase-2 pair-reads; LDS 33.8 -> 22.5 KB ->
//       6 blocks/CU),
//   (c) bias folded into MFMA C-init (saves 32 adds/edge).

#define BS 256
#define K1_EDGES 4096  // edges staged per block in scatter pass
#define P2_CAP 3072    // max edges per 128-dst range bucket (mean 2048, +22 sigma)

typedef float v2f __attribute__((ext_vector_type(2)));
typedef __attribute__((ext_vector_type(8))) short bf16x8;
typedef __attribute__((ext_vector_type(16))) float f32x16;
typedef __bf16 bf16v2 __attribute__((ext_vector_type(2)));

__device__ __forceinline__ unsigned ordenc(float f) {
    unsigned u = __float_as_uint(f);
    return (u & 0x80000000u) ? ~u : (u | 0x80000000u);
}
__device__ __forceinline__ float orddec(unsigned o) {
    unsigned u = (o & 0x80000000u) ? (o ^ 0x80000000u) : ~o;
    return __uint_as_float(u);
}
#define ORD_NEG_INF 0x007FFFFFu  // ordenc(-inf)

// two f32 -> packed bf16 pair (RNE) via v_cvt_pk_bf16_f32; x -> low half
__device__ __forceinline__ unsigned cvt2(float x, float y) {
    v2f v = {x, y};
    bf16v2 b = __builtin_convertvector(v, bf16v2);
    return __builtin_bit_cast(unsigned, b);
}
__device__ __forceinline__ float bflo(unsigned u) { return __uint_as_float(u << 16); }
__device__ __forceinline__ float bfhi(unsigned u) { return __uint_as_float(u & 0xFFFF0000u); }

// ---------------- utility kernels ----------------

__global__ __launch_bounds__(BS) void init_kernel(unsigned* __restrict__ a,
                                                  unsigned* __restrict__ b, int n32) {
    int i = blockIdx.x * BS + threadIdx.x;
    if (i < n32) {
        a[i] = ORD_NEG_INF;
        b[i] = ORD_NEG_INF;
    }
}

__global__ __launch_bounds__(BS) void finalize_kernel(unsigned* __restrict__ buf, int n) {
    int i = blockIdx.x * BS + threadIdx.x;
    if (i < n) {
        float v = orddec(buf[i]);
        reinterpret_cast<float*>(buf)[i] = fmaxf(v, 0.0f);
    }
}

// ---------------- pass 1a: per-block range histogram (LDS only) -------------
__global__ __launch_bounds__(BS) void bucket_hist_kernel(const int* __restrict__ ei, int E,
                                                         int NRP, int* __restrict__ blockHist) {
    __shared__ int hist[1024];
    const int tid = threadIdx.x;
    for (int r = tid; r < 1024; r += BS) hist[r] = 0;
    __syncthreads();
    const int base = blockIdx.x * K1_EDGES;
    const int M = min(K1_EDGES, E - base);
    for (int i = tid; i < M; i += BS) atomicAdd(&hist[ei[E + base + i] >> 7], 1);
    __syncthreads();
    for (int r = tid; r < NRP; r += BS) blockHist[blockIdx.x * NRP + r] = hist[r];
}

// ---------------- pass 2a: per-(block,range) LOCAL prefixes + range totals --
__global__ __launch_bounds__(512) void off_scan_kernel(const int* __restrict__ blockHist,
                                                       int NB1, int NRP,
                                                       int* __restrict__ off,
                                                       int* __restrict__ total) {
    const int r = (blockIdx.x * 512 + threadIdx.x) >> 6;
    const int lane = threadIdx.x & 63;
    if (r >= NRP) return;
    int carry = 0;
    const int chunks = (NB1 + 63) / 64;
    for (int c = 0; c < chunks; ++c) {
        const int b = c * 64 + lane;
        const int v = (b < NB1) ? blockHist[b * NRP + r] : 0;
        int x = v;
#pragma unroll
        for (int d = 1; d < 64; d <<= 1) {
            int y = __shfl_up(x, d, 64);
            if (lane >= d) x += y;
        }
        if (b < NB1) off[b * NRP + r] = carry + (x - v);
        carry += __shfl(x, 63, 64);
    }
    if (lane == 0) total[r] = carry;
}

// ---------------- pass 2b: exclusive scan of totals -> rangeBase ------------
__global__ __launch_bounds__(1024) void range_scan_kernel(const int* __restrict__ total,
                                                          int NRP, int* __restrict__ rangeBase) {
    __shared__ int s[1024];
    const int t = threadIdx.x;
    const int v = (t < NRP) ? total[t] : 0;
    s[t] = v;
    __syncthreads();
    for (int off = 1; off < 1024; off <<= 1) {
        int add = (t >= off) ? s[t - off] : 0;
        __syncthreads();
        s[t] += add;
        __syncthreads();
    }
    if (t < NRP) rangeBase[t] = s[t] - v;
}

// ---------------- pass 1b: LDS-ranked scatter into range buckets ------------
__global__ __launch_bounds__(BS) void bucket_scatter_kernel(
    const int* __restrict__ ei, int E, int NRP, const int* __restrict__ off,
    const int* __restrict__ rangeBase, int2* __restrict__ sedgeB) {
    __shared__ int2 stage[K1_EDGES];          // 32 KB
    __shared__ unsigned short inv[K1_EDGES];  // 8 KB
    __shared__ int hist[1024], start[1024], cursor[1024];
    __shared__ int ts[BS];
    const int tid = threadIdx.x;
    for (int r = tid; r < 1024; r += BS) hist[r] = 0;
    __syncthreads();
    const int base = blockIdx.x * K1_EDGES;
    const int M = min(K1_EDGES, E - base);
    for (int i = tid; i < M; i += BS) {
        const int2 p = make_int2(ei[base + i], ei[E + base + i]);
        stage[i] = p;
        atomicAdd(&hist[p.y >> 7], 1);
    }
    __syncthreads();
    {
        const int i0 = tid * 4;
        const int l0 = hist[i0], l1 = hist[i0 + 1], l2 = hist[i0 + 2], l3 = hist[i0 + 3];
        const int tsum = l0 + l1 + l2 + l3;
        ts[tid] = tsum;
        __syncthreads();
        for (int off2 = 1; off2 < BS; off2 <<= 1) {
            int add = (tid >= off2) ? ts[tid - off2] : 0;
            __syncthreads();
            ts[tid] += add;
            __syncthreads();
        }
        const int texcl = ts[tid] - tsum;
        start[i0] = texcl;
        start[i0 + 1] = texcl + l0;
        start[i0 + 2] = texcl + l0 + l1;
        start[i0 + 3] = texcl + l0 + l1 + l2;
        cursor[i0] = start[i0];
        cursor[i0 + 1] = start[i0 + 1];
        cursor[i0 + 2] = start[i0 + 2];
        cursor[i0 + 3] = start[i0 + 3];
    }
    __syncthreads();
    for (int i = tid; i < M; i += BS) {
        const int pos = atomicAdd(&cursor[stage[i].y >> 7], 1);
        inv[pos] = (unsigned short)i;
    }
    __syncthreads();
    const int* offb = off + blockIdx.x * NRP;
    for (int j = tid; j < M; j += BS) {
        const int2 p = stage[inv[j]];
        const int r = p.y >> 7;
        sedgeB[rangeBase[r] + offb[r] + (j - start[r])] = p;  // contiguous runs
    }
}

// ---------------- pass 3: in-LDS sort within each range bucket --------------
__global__ __launch_bounds__(BS) void bucket_sort_kernel(
    const int2* __restrict__ sedgeB, const int* __restrict__ rangeBase,
    const int* __restrict__ total, int N, int2* __restrict__ sedge, int* __restrict__ row_ptr,
    int* __restrict__ cnt) {
    __shared__ int2 stage[P2_CAP];
    __shared__ unsigned short inv[P2_CAP];
    __shared__ int hist[128], start[128], cursor[128];
    const int r = blockIdx.x;
    const int tid = threadIdx.x;
    const int base = rangeBase[r];
    const int M = total[r];
    const bool fast = (M <= P2_CAP);
    if (tid < 128) hist[tid] = 0;
    __syncthreads();
    if (fast) {
        for (int i = tid; i < M; i += BS) {
            const int2 p = sedgeB[base + i];
            stage[i] = p;
            atomicAdd(&hist[p.y & 127], 1);
        }
    } else {  // statistically never; correct slow path
        if (tid < 128) {
            int c = 0;
            for (int i = 0; i < M; ++i) c += ((sedgeB[base + i].y & 127) == tid);
            hist[tid] = c;
        }
    }
    __syncthreads();
    if (tid < 128) start[tid] = hist[tid];
    __syncthreads();
    for (int off2 = 1; off2 < 128; off2 <<= 1) {
        int add = 0;
        if (tid < 128 && tid >= off2) add = start[tid - off2];
        __syncthreads();
        if (tid < 128) start[tid] += add;
        __syncthreads();
    }
    if (tid < 128) {
        const int excl = start[tid] - hist[tid];
        start[tid] = excl;
        cursor[tid] = excl;
        const int node = r * 128 + tid;
        if (node < N) {
            row_ptr[node] = base + excl;
            cnt[node] = hist[tid];
        }
    }
    __syncthreads();
    if (fast) {
        for (int i = tid; i < M; i += BS) {
            const int pos = atomicAdd(&cursor[stage[i].y & 127], 1);
            inv[pos] = (unsigned short)i;
        }
        __syncthreads();
        for (int j = tid; j < M; j += BS) sedge[base + j] = stage[inv[j]];
    } else {
        if (tid < 128) {
            int c = base + start[tid];
            for (int i = 0; i < M; ++i) {
                const int2 p = sedgeB[base + i];
                if ((p.y & 127) == tid) sedge[c++] = p;
            }
        }
    }
}

// ---------------- per-node U/V precompute (U packed bf16, V f32) ------------
__global__ __launch_bounds__(BS) void prep1_kernel(const float* __restrict__ pos,
                                                   const float* __restrict__ Wa,
                                                   const float* __restrict__ ba,
                                                   unsigned* __restrict__ Ubf,
                                                   float* __restrict__ V, int N) {
    int n = blockIdx.x * BS + threadIdx.x;
    if (n >= N) return;
    const float p[3] = {pos[3 * n], pos[3 * n + 1], pos[3 * n + 2]};
    v2f u[16], v[16];
#pragma unroll
    for (int g = 0; g < 16; ++g) {
        u[g] = *reinterpret_cast<const v2f*>(&ba[g * 2]);
        v2f z = {0.0f, 0.0f};
        v[g] = z;
    }
#pragma unroll
    for (int i = 0; i < 3; ++i) {
        const v2f f = {p[i], p[i]};
#pragma unroll
        for (int g = 0; g < 16; ++g) {
            const v2f wA = *reinterpret_cast<const v2f*>(&Wa[i * 32 + g * 2]);
            const v2f wB = *reinterpret_cast<const v2f*>(&Wa[(i + 3) * 32 + g * 2]);
            u[g] = __builtin_elementwise_fma(f, wA + wB, u[g]);
            v[g] = __builtin_elementwise_fma(f, wB, v[g]);
        }
    }
    uint4* Up = reinterpret_cast<uint4*>(Ubf + (size_t)n * 16);
    float4* Vp = reinterpret_cast<float4*>(V + (size_t)n * 32);
#pragma unroll
    for (int q = 0; q < 4; ++q) {
        uint4 o;
        o.x = cvt2(u[4 * q + 0].x, u[4 * q + 0].y);
        o.y = cvt2(u[4 * q + 1].x, u[4 * q + 1].y);
        o.z = cvt2(u[4 * q + 2].x, u[4 * q + 2].y);
        o.w = cvt2(u[4 * q + 3].x, u[4 * q + 3].y);
        Up[q] = o;
    }
#pragma unroll
    for (int q = 0; q < 8; ++q)
        Vp[q] = make_float4(v[2 * q].x, v[2 * q].y, v[2 * q + 1].x, v[2 * q + 1].y);
}

// Layer 2 prep: reads layer-1 agg (ordered uint), decodes h inline.
__global__ __launch_bounds__(BS) void prep2_kernel(const float* __restrict__ pos,
                                                   const unsigned* __restrict__ aggA,
                                                   const float* __restrict__ Wa,
                                                   const float* __restrict__ ba,
                                                   unsigned* __restrict__ Ubf,
                                                   float* __restrict__ V, int N) {
    int n = blockIdx.x * BS + threadIdx.x;
    if (n >= N) return;
    float h[32];
    const uint4* hp = reinterpret_cast<const uint4*>(aggA + (size_t)n * 32);
#pragma unroll
    for (int q = 0; q < 8; ++q) {
        uint4 t = hp[q];
        h[4 * q + 0] = fmaxf(orddec(t.x), 0.0f);
        h[4 * q + 1] = fmaxf(orddec(t.y), 0.0f);
        h[4 * q + 2] = fmaxf(orddec(t.z), 0.0f);
        h[4 * q + 3] = fmaxf(orddec(t.w), 0.0f);
    }
    const float p[3] = {pos[3 * n], pos[3 * n + 1], pos[3 * n + 2]};
    v2f u[16], v[16];
#pragma unroll
    for (int g = 0; g < 16; ++g) {
        u[g] = *reinterpret_cast<const v2f*>(&ba[g * 2]);
        v2f z = {0.0f, 0.0f};
        v[g] = z;
    }
#pragma unroll
    for (int i = 0; i < 32; ++i) {
        const v2f f = {h[i], h[i]};
#pragma unroll
        for (int g = 0; g < 16; ++g) {
            const v2f w = *reinterpret_cast<const v2f*>(&Wa[i * 32 + g * 2]);
            u[g] = __builtin_elementwise_fma(f, w, u[g]);
        }
    }
#pragma unroll
    for (int i = 0; i < 3; ++i) {
        const v2f f = {p[i], p[i]};
#pragma unroll
        for (int g = 0; g < 16; ++g) {
            const v2f w = *reinterpret_cast<const v2f*>(&Wa[(32 + i) * 32 + g * 2]);
            u[g] = __builtin_elementwise_fma(f, w, u[g]);
            v[g] = __builtin_elementwise_fma(f, w, v[g]);
        }
    }
    uint4* Up = reinterpret_cast<uint4*>(Ubf + (size_t)n * 16);
    float4* Vp = reinterpret_cast<float4*>(V + (size_t)n * 32);
#pragma unroll
    for (int q = 0; q < 4; ++q) {
        uint4 o;
        o.x = cvt2(u[4 * q + 0].x, u[4 * q + 0].y);
        o.y = cvt2(u[4 * q + 1].x, u[4 * q + 1].y);
        o.z = cvt2(u[4 * q + 2].x, u[4 * q + 2].y);
        o.w = cvt2(u[4 * q + 3].x, u[4 * q + 3].y);
        Up[q] = o;
    }
#pragma unroll
    for (int q = 0; q < 8; ++q)
        Vp[q] = make_float4(v[2 * q].x, v[2 * q].y, v[2 * q + 1].x, v[2 * q + 1].y);
}

// ---------------- fused edge kernel: hid -> MFMA MLP2 -> segmented max ------
// LDS union (22528 B -> 6 blocks/CU):
//   phase A: dwords [0, 5120)   = hid packed bf16 pairs, [edge][20] (16 used)
//            dwords [5120,5632) = Wbt bf16 pairs, [n][16]
//   phase B: dwords [0, 4160)   = m matrix bf16 EDGE-pairs, [ch][130]
__global__ __launch_bounds__(BS, 6) void edge_seg_kernel(
    const unsigned* __restrict__ Ubf, const float4* __restrict__ V,
    const int* __restrict__ row_ptr, const int* __restrict__ cnt,
    const int2* __restrict__ sedge, const float* __restrict__ Wb,
    const float* __restrict__ bb, unsigned* __restrict__ agg, int E) {
    __shared__ __align__(16) unsigned lds[5632];

    const int tid = threadIdx.x;
    const int k0 = blockIdx.x * BS;
    const int blockEnd = min(k0 + BS, E);
    const int k = min(k0 + tid, E - 1);

    // stage Wbt: bf16 pairs, Wbt[n][pair p] = {Wb[2p][n], Wb[2p+1][n]}
    {
        const int n = tid & 31;
        const int p = (tid >> 5) * 2;
        lds[5120 + n * 16 + p + 0] = cvt2(Wb[(2 * p + 0) * 32 + n], Wb[(2 * p + 1) * 32 + n]);
        lds[5120 + n * 16 + p + 1] = cvt2(Wb[(2 * p + 2) * 32 + n], Wb[(2 * p + 3) * 32 + n]);
    }

    const int2 ed = sedge[k];
    {
        const uint4* Up = reinterpret_cast<const uint4*>(Ubf + (size_t)ed.x * 16);
        const float4* Vp = V + (size_t)ed.y * 8;
        const uint4 U0 = Up[0];
        const uint4 U1 = Up[1];
        const uint4 U2 = Up[2];
        const uint4 U3 = Up[3];
        const unsigned uu[16] = {U0.x, U0.y, U0.z, U0.w, U1.x, U1.y, U1.z, U1.w,
                                 U2.x, U2.y, U2.z, U2.w, U3.x, U3.y, U3.z, U3.w};
#pragma unroll
        for (int q = 0; q < 8; ++q) {
            const float4 vb = Vp[q];
            const unsigned a = uu[2 * q + 0];  // channels 4q, 4q+1
            const unsigned b = uu[2 * q + 1];  // channels 4q+2, 4q+3
            const float h0 = fmaxf(bflo(a) - vb.x, 0.0f);
            const float h1 = fmaxf(bfhi(a) - vb.y, 0.0f);
            const float h2 = fmaxf(bflo(b) - vb.z, 0.0f);
            const float h3 = fmaxf(bfhi(b) - vb.w, 0.0f);
            lds[tid * 20 + 2 * q + 0] = cvt2(h0, h1);
            lds[tid * 20 + 2 * q + 1] = cvt2(h2, h3);
        }
    }
    __syncthreads();

    const int l = tid & 63;
    const int w = tid >> 6;
    const int half = l >> 5;
    const int ln = l & 31;
    const uint4* ldsv = reinterpret_cast<const uint4*>(lds);

    const int e0 = 64 * w + ln;
    const int e1 = e0 + 32;
    const uint4 au00 = ldsv[e0 * 5 + half];
    const uint4 au01 = ldsv[e0 * 5 + half + 2];
    const uint4 au10 = ldsv[e1 * 5 + half];
    const uint4 au11 = ldsv[e1 * 5 + half + 2];
    const uint4 bu0 = ldsv[1280 + ln * 4 + half];
    const uint4 bu1 = ldsv[1280 + ln * 4 + half + 2];
    const float bbn = bb[ln];
    __syncthreads();

    // bias folded into C init (column n = ln gets bb[n])
    f32x16 c0, c1;
#pragma unroll
    for (int i = 0; i < 16; ++i) {
        c0[i] = bbn;
        c1[i] = bbn;
    }
    c0 = __builtin_amdgcn_mfma_f32_32x32x16_bf16(__builtin_bit_cast(bf16x8, au00),
                                                 __builtin_bit_cast(bf16x8, bu0), c0, 0, 0, 0);
    c0 = __builtin_amdgcn_mfma_f32_32x32x16_bf16(__builtin_bit_cast(bf16x8, au01),
                                                 __builtin_bit_cast(bf16x8, bu1), c0, 0, 0, 0);
    c1 = __builtin_amdgcn_mfma_f32_32x32x16_bf16(__builtin_bit_cast(bf16x8, au10),
                                                 __builtin_bit_cast(bf16x8, bu0), c1, 0, 0, 0);
    c1 = __builtin_amdgcn_mfma_f32_32x32x16_bf16(__builtin_bit_cast(bf16x8, au11),
                                                 __builtin_bit_cast(bf16x8, bu1), c1, 0, 0, 0);

    // write m as bf16 EDGE-pairs: C rows rr, rr+1 are consecutive edges.
    // smb[ch][ep] with stride 130 -> bank (2*ch + ep) % 32: 2-way max (free).
#pragma unroll
    for (int k2 = 0; k2 < 8; ++k2) {
        const int rr = 2 * k2;
        const int er = 64 * w + (rr & 3) + 8 * (rr >> 2) + 4 * half;  // even
        lds[ln * 130 + (er >> 1)] = cvt2(c0[rr], c0[rr + 1]);
        lds[ln * 130 + (er >> 1) + 16] = cvt2(c1[rr], c1[rr + 1]);
    }
    __syncthreads();

    // phase 2: segmented max; pair-reads along edges with odd-end fixups
    const int d0 = sedge[k0].y;
    const int d1 = sedge[blockEnd - 1].y;
    const int nPairs = (d1 - d0 + 1) * 32;
    for (int idx = tid; idx < nPairs; idx += BS) {
        const int c = idx & 31;
        const int n = d0 + (idx >> 5);
        const int rs = row_ptr[n];
        const int re = rs + cnt[n];
        const int s0 = max(rs, k0) - k0;
        const int s1 = min(re, blockEnd) - k0;
        if (s0 >= s1) continue;
        const unsigned* smc = &lds[c * 130];
        v2f m0 = {-INFINITY, -INFINITY};
        v2f m1 = m0;
        int e = s0;
        if (e & 1) {
            const unsigned u = smc[e >> 1];
            m0.x = fmaxf(m0.x, bfhi(u));
            ++e;
        }
        for (; e + 4 <= s1; e += 4) {
            const unsigned ua = smc[e >> 1];
            const unsigned ub = smc[(e >> 1) + 1];
            const v2f a = {bflo(ua), bfhi(ua)};
            const v2f b = {bflo(ub), bfhi(ub)};
            m0 = __builtin_elementwise_max(m0, a);
            m1 = __builtin_elementwise_max(m1, b);
        }
        if (e + 2 <= s1) {
            const unsigned u = smc[e >> 1];
            const v2f a = {bflo(u), bfhi(u)};
            m0 = __builtin_elementwise_max(m0, a);
            e += 2;
        }
        if (e < s1) m0.x = fmaxf(m0.x, bflo(smc[e >> 1]));
        const v2f mm = __builtin_elementwise_max(m0, m1);
        const float v = fmaxf(mm.x, mm.y);
        unsigned* p = &agg[(size_t)n * 32 + c];
        const unsigned enc = ordenc(v);
        if (rs >= k0 && re <= blockEnd)
            *p = enc;
        else
            atomicMax(p, enc);
    }
}

extern "C" void kernel_launch(void* const* d_in, const int* in_sizes, int n_in,
                              void* d_out, int out_size, void* d_ws, size_t ws_size,
                              hipStream_t stream) {
    const float* pos = (const float*)d_in[0];
    const int* ei = (const int*)d_in[1];
    const float* W1 = (const float*)d_in[3];
    const float* b1 = (const float*)d_in[4];
    const float* W2 = (const float*)d_in[5];
    const float* b2 = (const float*)d_in[6];
    const float* W3 = (const float*)d_in[7];
    const float* b3 = (const float*)d_in[8];
    const float* W4 = (const float*)d_in[9];
    const float* b4 = (const float*)d_in[10];

    const int E = in_sizes[1] / 2;
    const int N = in_sizes[0] / 3;
    const int n32 = N * 32;
    const int NPAD = ((N + BS - 1) / BS) * BS;
    const int EB = (E + BS - 1) / BS;
    const int NR = (N + 127) / 128;         // ranges of 128 dsts
    const int NRP = ((NR + 15) / 16) * 16;  // padded (<= 1024)
    const int NB1 = (E + K1_EDGES - 1) / K1_EDGES;
    const int BH = NB1 * NRP;

    int* cnt = (int*)d_ws;                    // NPAD
    int* row_ptr = cnt + NPAD;                // NPAD
    int* blockHist = row_ptr + NPAD;          // BH
    int* off = blockHist + BH;                // BH
    int* total = off + BH;                    // NRP
    int* rangeBase = total + NRP;             // NRP
    int2* sedge = (int2*)(rangeBase + NRP);   // E (offsets all mult-of-4 ints)
    unsigned* aggA = (unsigned*)(sedge + E);  // n32 (ord-encoded; prep2 decodes)
    unsigned* Ubf = aggA + n32;               // NPAD*16 (bf16-packed U)
    float* Vbuf = (float*)(Ubf + (size_t)NPAD * 16);  // n32
    int2* sedgeB = (int2*)Ubf;  // aliases Ubf+Vbuf (dead before prep1 writes)
    unsigned* aggB = (unsigned*)d_out;

    const int gridN32 = (n32 + BS - 1) / BS;
    const int NBn = (N + BS - 1) / BS;

    init_kernel<<<gridN32, BS, 0, stream>>>(aggA, aggB, n32);

    // --- atomic-free bucket sort -> sedge, row_ptr, cnt ---
    bucket_hist_kernel<<<NB1, BS, 0, stream>>>(ei, E, NRP, blockHist);
    off_scan_kernel<<<(NRP * 64 + 511) / 512, 512, 0, stream>>>(blockHist, NB1, NRP, off,
                                                                total);
    range_scan_kernel<<<1, 1024, 0, stream>>>(total, NRP, rangeBase);
    bucket_scatter_kernel<<<NB1, BS, 0, stream>>>(ei, E, NRP, off, rangeBase, sedgeB);
    bucket_sort_kernel<<<NR, BS, 0, stream>>>(sedgeB, rangeBase, total, N, sedge, row_ptr, cnt);

    // --- layer 1 ---
    prep1_kernel<<<NBn, BS, 0, stream>>>(pos, W1, b1, Ubf, Vbuf, N);
    edge_seg_kernel<<<EB, BS, 0, stream>>>(Ubf, (const float4*)Vbuf, row_ptr, cnt, sedge, W2,
                                           b2, aggA, E);
    // --- layer 2 ---
    prep2_kernel<<<NBn, BS, 0, stream>>>(pos, aggA, W3, b3, Ubf, Vbuf, N);
    edge_seg_kernel<<<EB, BS, 0, stream>>>(Ubf, (const float4*)Vbuf, row_ptr, cnt, sedge, W4,
                                           b4, aggB, E);
    finalize_kernel<<<gridN32, BS, 0, stream>>>(aggB, n32);
}

// Round 15
// 230.682 us; speedup vs baseline: 1.3934x; 1.0085x over previous
//
#include <hip/hip_runtime.h>
#include <hip/hip_bf16.h>
#include <stdint.h>

// PointNet EdgeConv, 2 layers. Round 15.
// R10: atomic-free bucket sort + MFMA edge_seg.                278 us
// R13: U table packed bf16 (gather 128 -> 64 B).               257 us
// R14: cvt_pk_bf16 + bf16 m-matrix + bias-in-C.                233 us <- best
// R15: (a) init+hist+prep1 fused into one setup_kernel (11 -> 9 launches,
//          latency overlap); sedgeB gets dedicated ws (no more Ubf alias);
//      (b) 512-edge edge_seg blocks (8 waves, LDS 43 KB, 3 blk/CU = same
//          24 waves/CU but half the barriers/straddlers/fixed costs).

#define BS 256
#define EBS 512        // edge_seg block size (512 edges per block)
#define K1_EDGES 4096  // edges staged per block in scatter pass
#define P2_CAP 3072    // max edges per 128-dst range bucket (mean 2048, +22 sigma)

typedef float v2f __attribute__((ext_vector_type(2)));
typedef __attribute__((ext_vector_type(8))) short bf16x8;
typedef __attribute__((ext_vector_type(16))) float f32x16;
typedef __bf16 bf16v2 __attribute__((ext_vector_type(2)));

__device__ __forceinline__ unsigned ordenc(float f) {
    unsigned u = __float_as_uint(f);
    return (u & 0x80000000u) ? ~u : (u | 0x80000000u);
}
__device__ __forceinline__ float orddec(unsigned o) {
    unsigned u = (o & 0x80000000u) ? (o ^ 0x80000000u) : ~o;
    return __uint_as_float(u);
}
#define ORD_NEG_INF 0x007FFFFFu  // ordenc(-inf)

// two f32 -> packed bf16 pair (RNE) via v_cvt_pk_bf16_f32; x -> low half
__device__ __forceinline__ unsigned cvt2(float x, float y) {
    v2f v = {x, y};
    bf16v2 b = __builtin_convertvector(v, bf16v2);
    return __builtin_bit_cast(unsigned, b);
}
__device__ __forceinline__ float bflo(unsigned u) { return __uint_as_float(u << 16); }
__device__ __forceinline__ float bfhi(unsigned u) { return __uint_as_float(u & 0xFFFF0000u); }

// ---------------- fused setup: range-hist | prep1 | agg-init ----------------
// Blocks [0, NB1)            : per-block range histogram of dst>>7
// Blocks [NB1, NB1+NBn)      : prep1 (U bf16 / V f32 for layer 1)
// Blocks [NB1+NBn, +gridN32) : init aggA/aggB to ORD_NEG_INF
__global__ __launch_bounds__(BS) void setup_kernel(
    const int* __restrict__ ei, int E, int NRP, int* __restrict__ blockHist,
    const float* __restrict__ pos, const float* __restrict__ Wa, const float* __restrict__ ba,
    unsigned* __restrict__ Ubf, float* __restrict__ V, int N, unsigned* __restrict__ aggA,
    unsigned* __restrict__ aggB, int n32, int NB1, int NBn) {
    __shared__ int hist[1024];
    const int tid = threadIdx.x;
    const int b = blockIdx.x;
    if (b < NB1) {
        for (int r = tid; r < 1024; r += BS) hist[r] = 0;
        __syncthreads();
        const int base = b * K1_EDGES;
        const int M = min(K1_EDGES, E - base);
        for (int i = tid; i < M; i += BS) atomicAdd(&hist[ei[E + base + i] >> 7], 1);
        __syncthreads();
        for (int r = tid; r < NRP; r += BS) blockHist[b * NRP + r] = hist[r];
    } else if (b < NB1 + NBn) {
        const int n = (b - NB1) * BS + tid;
        if (n >= N) return;
        const float p[3] = {pos[3 * n], pos[3 * n + 1], pos[3 * n + 2]};
        v2f u[16], v[16];
#pragma unroll
        for (int g = 0; g < 16; ++g) {
            u[g] = *reinterpret_cast<const v2f*>(&ba[g * 2]);
            v2f z = {0.0f, 0.0f};
            v[g] = z;
        }
#pragma unroll
        for (int i = 0; i < 3; ++i) {
            const v2f f = {p[i], p[i]};
#pragma unroll
            for (int g = 0; g < 16; ++g) {
                const v2f wA = *reinterpret_cast<const v2f*>(&Wa[i * 32 + g * 2]);
                const v2f wB = *reinterpret_cast<const v2f*>(&Wa[(i + 3) * 32 + g * 2]);
                u[g] = __builtin_elementwise_fma(f, wA + wB, u[g]);
                v[g] = __builtin_elementwise_fma(f, wB, v[g]);
            }
        }
        uint4* Up = reinterpret_cast<uint4*>(Ubf + (size_t)n * 16);
        float4* Vp = reinterpret_cast<float4*>(V + (size_t)n * 32);
#pragma unroll
        for (int q = 0; q < 4; ++q) {
            uint4 o;
            o.x = cvt2(u[4 * q + 0].x, u[4 * q + 0].y);
            o.y = cvt2(u[4 * q + 1].x, u[4 * q + 1].y);
            o.z = cvt2(u[4 * q + 2].x, u[4 * q + 2].y);
            o.w = cvt2(u[4 * q + 3].x, u[4 * q + 3].y);
            Up[q] = o;
        }
#pragma unroll
        for (int q = 0; q < 8; ++q)
            Vp[q] = make_float4(v[2 * q].x, v[2 * q].y, v[2 * q + 1].x, v[2 * q + 1].y);
    } else {
        const int i = (b - NB1 - NBn) * BS + tid;
        if (i < n32) {
            aggA[i] = ORD_NEG_INF;
            aggB[i] = ORD_NEG_INF;
        }
    }
}

__global__ __launch_bounds__(BS) void finalize_kernel(unsigned* __restrict__ buf, int n) {
    int i = blockIdx.x * BS + threadIdx.x;
    if (i < n) {
        float v = orddec(buf[i]);
        reinterpret_cast<float*>(buf)[i] = fmaxf(v, 0.0f);
    }
}

// ---------------- pass 2a: per-(block,range) LOCAL prefixes + range totals --
__global__ __launch_bounds__(512) void off_scan_kernel(const int* __restrict__ blockHist,
                                                       int NB1, int NRP,
                                                       int* __restrict__ off,
                                                       int* __restrict__ total) {
    const int r = (blockIdx.x * 512 + threadIdx.x) >> 6;
    const int lane = threadIdx.x & 63;
    if (r >= NRP) return;
    int carry = 0;
    const int chunks = (NB1 + 63) / 64;
    for (int c = 0; c < chunks; ++c) {
        const int b = c * 64 + lane;
        const int v = (b < NB1) ? blockHist[b * NRP + r] : 0;
        int x = v;
#pragma unroll
        for (int d = 1; d < 64; d <<= 1) {
            int y = __shfl_up(x, d, 64);
            if (lane >= d) x += y;
        }
        if (b < NB1) off[b * NRP + r] = carry + (x - v);
        carry += __shfl(x, 63, 64);
    }
    if (lane == 0) total[r] = carry;
}

// ---------------- pass 2b: exclusive scan of totals -> rangeBase ------------
__global__ __launch_bounds__(1024) void range_scan_kernel(const int* __restrict__ total,
                                                          int NRP, int* __restrict__ rangeBase) {
    __shared__ int s[1024];
    const int t = threadIdx.x;
    const int v = (t < NRP) ? total[t] : 0;
    s[t] = v;
    __syncthreads();
    for (int off = 1; off < 1024; off <<= 1) {
        int add = (t >= off) ? s[t - off] : 0;
        __syncthreads();
        s[t] += add;
        __syncthreads();
    }
    if (t < NRP) rangeBase[t] = s[t] - v;
}

// ---------------- pass 1b: LDS-ranked scatter into range buckets ------------
__global__ __launch_bounds__(BS) void bucket_scatter_kernel(
    const int* __restrict__ ei, int E, int NRP, const int* __restrict__ off,
    const int* __restrict__ rangeBase, int2* __restrict__ sedgeB) {
    __shared__ int2 stage[K1_EDGES];          // 32 KB
    __shared__ unsigned short inv[K1_EDGES];  // 8 KB
    __shared__ int hist[1024], start[1024], cursor[1024];
    __shared__ int ts[BS];
    const int tid = threadIdx.x;
    for (int r = tid; r < 1024; r += BS) hist[r] = 0;
    __syncthreads();
    const int base = blockIdx.x * K1_EDGES;
    const int M = min(K1_EDGES, E - base);
    for (int i = tid; i < M; i += BS) {
        const int2 p = make_int2(ei[base + i], ei[E + base + i]);
        stage[i] = p;
        atomicAdd(&hist[p.y >> 7], 1);
    }
    __syncthreads();
    {
        const int i0 = tid * 4;
        const int l0 = hist[i0], l1 = hist[i0 + 1], l2 = hist[i0 + 2], l3 = hist[i0 + 3];
        const int tsum = l0 + l1 + l2 + l3;
        ts[tid] = tsum;
        __syncthreads();
        for (int off2 = 1; off2 < BS; off2 <<= 1) {
            int add = (tid >= off2) ? ts[tid - off2] : 0;
            __syncthreads();
            ts[tid] += add;
            __syncthreads();
        }
        const int texcl = ts[tid] - tsum;
        start[i0] = texcl;
        start[i0 + 1] = texcl + l0;
        start[i0 + 2] = texcl + l0 + l1;
        start[i0 + 3] = texcl + l0 + l1 + l2;
        cursor[i0] = start[i0];
        cursor[i0 + 1] = start[i0 + 1];
        cursor[i0 + 2] = start[i0 + 2];
        cursor[i0 + 3] = start[i0 + 3];
    }
    __syncthreads();
    for (int i = tid; i < M; i += BS) {
        const int pos = atomicAdd(&cursor[stage[i].y >> 7], 1);
        inv[pos] = (unsigned short)i;
    }
    __syncthreads();
    const int* offb = off + blockIdx.x * NRP;
    for (int j = tid; j < M; j += BS) {
        const int2 p = stage[inv[j]];
        const int r = p.y >> 7;
        sedgeB[rangeBase[r] + offb[r] + (j - start[r])] = p;  // contiguous runs
    }
}

// ---------------- pass 3: in-LDS sort within each range bucket --------------
__global__ __launch_bounds__(BS) void bucket_sort_kernel(
    const int2* __restrict__ sedgeB, const int* __restrict__ rangeBase,
    const int* __restrict__ total, int N, int2* __restrict__ sedge, int* __restrict__ row_ptr,
    int* __restrict__ cnt) {
    __shared__ int2 stage[P2_CAP];
    __shared__ unsigned short inv[P2_CAP];
    __shared__ int hist[128], start[128], cursor[128];
    const int r = blockIdx.x;
    const int tid = threadIdx.x;
    const int base = rangeBase[r];
    const int M = total[r];
    const bool fast = (M <= P2_CAP);
    if (tid < 128) hist[tid] = 0;
    __syncthreads();
    if (fast) {
        for (int i = tid; i < M; i += BS) {
            const int2 p = sedgeB[base + i];
            stage[i] = p;
            atomicAdd(&hist[p.y & 127], 1);
        }
    } else {  // statistically never; correct slow path
        if (tid < 128) {
            int c = 0;
            for (int i = 0; i < M; ++i) c += ((sedgeB[base + i].y & 127) == tid);
            hist[tid] = c;
        }
    }
    __syncthreads();
    if (tid < 128) start[tid] = hist[tid];
    __syncthreads();
    for (int off2 = 1; off2 < 128; off2 <<= 1) {
        int add = 0;
        if (tid < 128 && tid >= off2) add = start[tid - off2];
        __syncthreads();
        if (tid < 128) start[tid] += add;
        __syncthreads();
    }
    if (tid < 128) {
        const int excl = start[tid] - hist[tid];
        start[tid] = excl;
        cursor[tid] = excl;
        const int node = r * 128 + tid;
        if (node < N) {
            row_ptr[node] = base + excl;
            cnt[node] = hist[tid];
        }
    }
    __syncthreads();
    if (fast) {
        for (int i = tid; i < M; i += BS) {
            const int pos = atomicAdd(&cursor[stage[i].y & 127], 1);
            inv[pos] = (unsigned short)i;
        }
        __syncthreads();
        for (int j = tid; j < M; j += BS) sedge[base + j] = stage[inv[j]];
    } else {
        if (tid < 128) {
            int c = base + start[tid];
            for (int i = 0; i < M; ++i) {
                const int2 p = sedgeB[base + i];
                if ((p.y & 127) == tid) sedge[c++] = p;
            }
        }
    }
}

// Layer 2 prep: reads layer-1 agg (ordered uint), decodes h inline.
__global__ __launch_bounds__(BS) void prep2_kernel(const float* __restrict__ pos,
                                                   const unsigned* __restrict__ aggA,
                                                   const float* __restrict__ Wa,
                                                   const float* __restrict__ ba,
                                                   unsigned* __restrict__ Ubf,
                                                   float* __restrict__ V, int N) {
    int n = blockIdx.x * BS + threadIdx.x;
    if (n >= N) return;
    float h[32];
    const uint4* hp = reinterpret_cast<const uint4*>(aggA + (size_t)n * 32);
#pragma unroll
    for (int q = 0; q < 8; ++q) {
        uint4 t = hp[q];
        h[4 * q + 0] = fmaxf(orddec(t.x), 0.0f);
        h[4 * q + 1] = fmaxf(orddec(t.y), 0.0f);
        h[4 * q + 2] = fmaxf(orddec(t.z), 0.0f);
        h[4 * q + 3] = fmaxf(orddec(t.w), 0.0f);
    }
    const float p[3] = {pos[3 * n], pos[3 * n + 1], pos[3 * n + 2]};
    v2f u[16], v[16];
#pragma unroll
    for (int g = 0; g < 16; ++g) {
        u[g] = *reinterpret_cast<const v2f*>(&ba[g * 2]);
        v2f z = {0.0f, 0.0f};
        v[g] = z;
    }
#pragma unroll
    for (int i = 0; i < 32; ++i) {
        const v2f f = {h[i], h[i]};
#pragma unroll
        for (int g = 0; g < 16; ++g) {
            const v2f w = *reinterpret_cast<const v2f*>(&Wa[i * 32 + g * 2]);
            u[g] = __builtin_elementwise_fma(f, w, u[g]);
        }
    }
#pragma unroll
    for (int i = 0; i < 3; ++i) {
        const v2f f = {p[i], p[i]};
#pragma unroll
        for (int g = 0; g < 16; ++g) {
            const v2f w = *reinterpret_cast<const v2f*>(&Wa[(32 + i) * 32 + g * 2]);
            u[g] = __builtin_elementwise_fma(f, w, u[g]);
            v[g] = __builtin_elementwise_fma(f, w, v[g]);
        }
    }
    uint4* Up = reinterpret_cast<uint4*>(Ubf + (size_t)n * 16);
    float4* Vp = reinterpret_cast<float4*>(V + (size_t)n * 32);
#pragma unroll
    for (int q = 0; q < 4; ++q) {
        uint4 o;
        o.x = cvt2(u[4 * q + 0].x, u[4 * q + 0].y);
        o.y = cvt2(u[4 * q + 1].x, u[4 * q + 1].y);
        o.z = cvt2(u[4 * q + 2].x, u[4 * q + 2].y);
        o.w = cvt2(u[4 * q + 3].x, u[4 * q + 3].y);
        Up[q] = o;
    }
#pragma unroll
    for (int q = 0; q < 8; ++q)
        Vp[q] = make_float4(v[2 * q].x, v[2 * q].y, v[2 * q + 1].x, v[2 * q + 1].y);
}

// ---------------- fused edge kernel (512 edges/block) -----------------------
// LDS union (43008 B -> 3 blocks/CU x 8 waves = 24 waves/CU):
//   phase A: dwords [0, 10240)     = hid bf16 pairs, [edge][20] (16 used)
//            dwords [10240, 10752) = Wbt bf16 pairs, [n][16]
//   phase B: dwords [0, 8256)      = m bf16 EDGE-pairs, [ch][258]
__global__ __launch_bounds__(EBS, 6) void edge_seg_kernel(
    const unsigned* __restrict__ Ubf, const float4* __restrict__ V,
    const int* __restrict__ row_ptr, const int* __restrict__ cnt,
    const int2* __restrict__ sedge, const float* __restrict__ Wb,
    const float* __restrict__ bb, unsigned* __restrict__ agg, int E) {
    __shared__ __align__(16) unsigned lds[10752];

    const int tid = threadIdx.x;
    const int k0 = blockIdx.x * EBS;
    const int blockEnd = min(k0 + EBS, E);
    const int k = min(k0 + tid, E - 1);

    // stage Wbt: bf16 pairs, Wbt[n][pair p] = {Wb[2p][n], Wb[2p+1][n]}
    if (tid < 256) {
        const int n = tid & 31;
        const int p = (tid >> 5) * 2;
        lds[10240 + n * 16 + p + 0] = cvt2(Wb[(2 * p + 0) * 32 + n], Wb[(2 * p + 1) * 32 + n]);
        lds[10240 + n * 16 + p + 1] = cvt2(Wb[(2 * p + 2) * 32 + n], Wb[(2 * p + 3) * 32 + n]);
    }

    const int2 ed = sedge[k];
    {
        const uint4* Up = reinterpret_cast<const uint4*>(Ubf + (size_t)ed.x * 16);
        const float4* Vp = V + (size_t)ed.y * 8;
        const uint4 U0 = Up[0];
        const uint4 U1 = Up[1];
        const uint4 U2 = Up[2];
        const uint4 U3 = Up[3];
        const unsigned uu[16] = {U0.x, U0.y, U0.z, U0.w, U1.x, U1.y, U1.z, U1.w,
                                 U2.x, U2.y, U2.z, U2.w, U3.x, U3.y, U3.z, U3.w};
#pragma unroll
        for (int q = 0; q < 8; ++q) {
            const float4 vb = Vp[q];
            const unsigned a = uu[2 * q + 0];  // channels 4q, 4q+1
            const unsigned b = uu[2 * q + 1];  // channels 4q+2, 4q+3
            const float h0 = fmaxf(bflo(a) - vb.x, 0.0f);
            const float h1 = fmaxf(bfhi(a) - vb.y, 0.0f);
            const float h2 = fmaxf(bflo(b) - vb.z, 0.0f);
            const float h3 = fmaxf(bfhi(b) - vb.w, 0.0f);
            lds[tid * 20 + 2 * q + 0] = cvt2(h0, h1);
            lds[tid * 20 + 2 * q + 1] = cvt2(h2, h3);
        }
    }
    __syncthreads();

    const int l = tid & 63;
    const int w = tid >> 6;  // 0..7, wave w covers edges 64w..64w+63
    const int half = l >> 5;
    const int ln = l & 31;
    const uint4* ldsv = reinterpret_cast<const uint4*>(lds);

    const int e0 = 64 * w + ln;
    const int e1 = e0 + 32;
    const uint4 au00 = ldsv[e0 * 5 + half];
    const uint4 au01 = ldsv[e0 * 5 + half + 2];
    const uint4 au10 = ldsv[e1 * 5 + half];
    const uint4 au11 = ldsv[e1 * 5 + half + 2];
    const uint4 bu0 = ldsv[2560 + ln * 4 + half];
    const uint4 bu1 = ldsv[2560 + ln * 4 + half + 2];
    const float bbn = bb[ln];
    __syncthreads();

    // bias folded into C init (column n = ln gets bb[n])
    f32x16 c0, c1;
#pragma unroll
    for (int i = 0; i < 16; ++i) {
        c0[i] = bbn;
        c1[i] = bbn;
    }
    c0 = __builtin_amdgcn_mfma_f32_32x32x16_bf16(__builtin_bit_cast(bf16x8, au00),
                                                 __builtin_bit_cast(bf16x8, bu0), c0, 0, 0, 0);
    c0 = __builtin_amdgcn_mfma_f32_32x32x16_bf16(__builtin_bit_cast(bf16x8, au01),
                                                 __builtin_bit_cast(bf16x8, bu1), c0, 0, 0, 0);
    c1 = __builtin_amdgcn_mfma_f32_32x32x16_bf16(__builtin_bit_cast(bf16x8, au10),
                                                 __builtin_bit_cast(bf16x8, bu0), c1, 0, 0, 0);
    c1 = __builtin_amdgcn_mfma_f32_32x32x16_bf16(__builtin_bit_cast(bf16x8, au11),
                                                 __builtin_bit_cast(bf16x8, bu1), c1, 0, 0, 0);

    // write m as bf16 EDGE-pairs: C rows rr, rr+1 are consecutive edges.
    // smb[ch][ep] stride 258 -> bank (2*ch + ep) % 32: 2-way max (free).
#pragma unroll
    for (int k2 = 0; k2 < 8; ++k2) {
        const int rr = 2 * k2;
        const int er = 64 * w + (rr & 3) + 8 * (rr >> 2) + 4 * half;  // even
        lds[ln * 258 + (er >> 1)] = cvt2(c0[rr], c0[rr + 1]);
        lds[ln * 258 + (er >> 1) + 16] = cvt2(c1[rr], c1[rr + 1]);
    }
    __syncthreads();

    // phase 2: segmented max; pair-reads along edges with odd-end fixups
    const int d0 = sedge[k0].y;
    const int d1 = sedge[blockEnd - 1].y;
    const int nPairs = (d1 - d0 + 1) * 32;
    for (int idx = tid; idx < nPairs; idx += EBS) {
        const int c = idx & 31;
        const int n = d0 + (idx >> 5);
        const int rs = row_ptr[n];
        const int re = rs + cnt[n];
        const int s0 = max(rs, k0) - k0;
        const int s1 = min(re, blockEnd) - k0;
        if (s0 >= s1) continue;
        const unsigned* smc = &lds[c * 258];
        v2f m0 = {-INFINITY, -INFINITY};
        v2f m1 = m0;
        int e = s0;
        if (e & 1) {
            const unsigned u = smc[e >> 1];
            m0.x = fmaxf(m0.x, bfhi(u));
            ++e;
        }
        for (; e + 4 <= s1; e += 4) {
            const unsigned ua = smc[e >> 1];
            const unsigned ub = smc[(e >> 1) + 1];
            const v2f a = {bflo(ua), bfhi(ua)};
            const v2f b = {bflo(ub), bfhi(ub)};
            m0 = __builtin_elementwise_max(m0, a);
            m1 = __builtin_elementwise_max(m1, b);
        }
        if (e + 2 <= s1) {
            const unsigned u = smc[e >> 1];
            const v2f a = {bflo(u), bfhi(u)};
            m0 = __builtin_elementwise_max(m0, a);
            e += 2;
        }
        if (e < s1) m0.x = fmaxf(m0.x, bflo(smc[e >> 1]));
        const v2f mm = __builtin_elementwise_max(m0, m1);
        const float v = fmaxf(mm.x, mm.y);
        unsigned* p = &agg[(size_t)n * 32 + c];
        const unsigned enc = ordenc(v);
        if (rs >= k0 && re <= blockEnd)
            *p = enc;
        else
            atomicMax(p, enc);
    }
}

extern "C" void kernel_launch(void* const* d_in, const int* in_sizes, int n_in,
                              void* d_out, int out_size, void* d_ws, size_t ws_size,
                              hipStream_t stream) {
    const float* pos = (const float*)d_in[0];
    const int* ei = (const int*)d_in[1];
    const float* W1 = (const float*)d_in[3];
    const float* b1 = (const float*)d_in[4];
    const float* W2 = (const float*)d_in[5];
    const float* b2 = (const float*)d_in[6];
    const float* W3 = (const float*)d_in[7];
    const float* b3 = (const float*)d_in[8];
    const float* W4 = (const float*)d_in[9];
    const float* b4 = (const float*)d_in[10];

    const int E = in_sizes[1] / 2;
    const int N = in_sizes[0] / 3;
    const int n32 = N * 32;
    const int NPAD = ((N + BS - 1) / BS) * BS;
    const int EB2 = (E + EBS - 1) / EBS;
    const int NR = (N + 127) / 128;         // ranges of 128 dsts
    const int NRP = ((NR + 15) / 16) * 16;  // padded (<= 1024)
    const int NB1 = (E + K1_EDGES - 1) / K1_EDGES;
    const int BH = NB1 * NRP;

    int* cnt = (int*)d_ws;                    // NPAD
    int* row_ptr = cnt + NPAD;                // NPAD
    int* blockHist = row_ptr + NPAD;          // BH
    int* off = blockHist + BH;                // BH
    int* total = off + BH;                    // NRP
    int* rangeBase = total + NRP;             // NRP
    int2* sedge = (int2*)(rangeBase + NRP);   // E (offsets all mult-of-4 ints)
    int2* sedgeB = sedge + E;                 // E (dedicated — no aliasing now)
    unsigned* aggA = (unsigned*)(sedgeB + E);         // n32
    unsigned* Ubf = aggA + n32;                       // NPAD*16 (bf16-packed U)
    float* Vbuf = (float*)(Ubf + (size_t)NPAD * 16);  // n32
    unsigned* aggB = (unsigned*)d_out;

    const int gridN32 = (n32 + BS - 1) / BS;
    const int NBn = (N + BS - 1) / BS;

    // fused: hist | prep1 | agg-init (mutually independent)
    setup_kernel<<<NB1 + NBn + gridN32, BS, 0, stream>>>(ei, E, NRP, blockHist, pos, W1, b1,
                                                         Ubf, Vbuf, N, aggA, aggB, n32, NB1,
                                                         NBn);
    off_scan_kernel<<<(NRP * 64 + 511) / 512, 512, 0, stream>>>(blockHist, NB1, NRP, off,
                                                                total);
    range_scan_kernel<<<1, 1024, 0, stream>>>(total, NRP, rangeBase);
    bucket_scatter_kernel<<<NB1, BS, 0, stream>>>(ei, E, NRP, off, rangeBase, sedgeB);
    bucket_sort_kernel<<<NR, BS, 0, stream>>>(sedgeB, rangeBase, total, N, sedge, row_ptr, cnt);

    // --- layer 1 ---
    edge_seg_kernel<<<EB2, EBS, 0, stream>>>(Ubf, (const float4*)Vbuf, row_ptr, cnt, sedge, W2,
                                             b2, aggA, E);
    // --- layer 2 ---
    prep2_kernel<<<NBn, BS, 0, stream>>>(pos, aggA, W3, b3, Ubf, Vbuf, N);
    edge_seg_kernel<<<EB2, EBS, 0, stream>>>(Ubf, (const float4*)Vbuf, row_ptr, cnt, sedge, W4,
                                             b4, aggB, E);
    finalize_kernel<<<gridN32, BS, 0, stream>>>(aggB, n32);
}